// Round 8
// baseline (1197.158 us; speedup 1.0000x reference)
//
#include <hip/hip_runtime.h>
#include <stdint.h>

// Problem constants (B, D, L, K from the reference). fp32 I/O per reference.
#define NB 4096
#define DD 2048
#define LL 16384
#define KT 64
#define WCAP 24        // window candidate cap per row
#define TAU 1.2e-2f    // sure/window margin: 5.7 sigma of zhat error (hh-only)
#define T3 1e-4f       // tier-3 exact-fp64 gap threshold (matches round-3 exposure)
#define CCAP 2048      // candidate-list cap (|z|>=2.0 expected ~500-1000)

typedef unsigned short u16;
typedef __bf16 bf16x8 __attribute__((ext_vector_type(8)));
typedef float f32x4 __attribute__((ext_vector_type(4)));
typedef unsigned short u16x4 __attribute__((ext_vector_type(4)));
typedef unsigned short u16x8 __attribute__((ext_vector_type(8)));

__device__ __forceinline__ float bf2f(u16 b) {
  return __uint_as_float(((unsigned)b) << 16);
}
__device__ __forceinline__ u16 f2bf(float f) {
  unsigned u = __float_as_uint(f);
  unsigned r = u + 0x7fffu + ((u >> 16) & 1u);  // RNE
  return (u16)(r >> 16);
}

// ---------------------------------------------------------------------------
// Kernel 1: X fp32 -> Xh bf16 (hi part only; fixup reads fp32 X directly)
// ---------------------------------------------------------------------------
__global__ __launch_bounds__(256) void prep_x(const float* __restrict__ X,
                                              u16* __restrict__ Xh) {
  int i = (blockIdx.x * 256 + threadIdx.x) * 4;
  float4 v = *(const float4*)(X + i);
  u16x4 h;
  h[0] = f2bf(v.x); h[1] = f2bf(v.y); h[2] = f2bf(v.z); h[3] = f2bf(v.w);
  *(u16x4*)(Xh + i) = h;
}

// ---------------------------------------------------------------------------
// Kernel 2: transpose + split W fp32 [2048,16384] -> Wh/Wl bf16 [16384,2048]
// AND fp32 transposed copy Wt [16384,2048] (tier-3 contiguous rows).
// ---------------------------------------------------------------------------
__global__ __launch_bounds__(256) void prep_w(const float* __restrict__ W,
                                              u16* __restrict__ Wh,
                                              u16* __restrict__ Wl,
                                              float* __restrict__ Wt) {
  __shared__ float tile[64][65];  // +1 pad breaks write-phase bank aliasing
  int l0 = blockIdx.x * 64, d0 = blockIdx.y * 64;
  int t = threadIdx.x;
  int lx = (t & 15) * 4;
  int dq = t >> 4;
#pragma unroll
  for (int p = 0; p < 4; ++p) {
    int d = dq + p * 16;
    float4 v = *(const float4*)(W + (size_t)(d0 + d) * LL + l0 + lx);
    tile[d][lx + 0] = v.x; tile[d][lx + 1] = v.y;
    tile[d][lx + 2] = v.z; tile[d][lx + 3] = v.w;
  }
  __syncthreads();
  int dx = (t & 15) * 4;
  int lq = t >> 4;
#pragma unroll
  for (int p = 0; p < 4; ++p) {
    int l = lq + p * 16;
    u16x4 h, lo;
    float4 wv;
#pragma unroll
    for (int q = 0; q < 4; ++q) {
      float w = tile[dx + q][l];
      u16 hb = f2bf(w);
      h[q] = hb;
      lo[q] = f2bf(w - bf2f(hb));
      ((float*)&wv)[q] = w;
    }
    size_t o = (size_t)(l0 + l) * DD + d0 + dx;
    *(u16x4*)(Wh + o) = h;
    *(u16x4*)(Wl + o) = lo;
    *(float4*)(Wt + o) = wv;
  }
}

// ---------------------------------------------------------------------------
// Kernel 3: encode GEMM  zhat = Xh·Wh^T + benc
// 256x256 tile, BK=64, 8 waves (2Mx4N, 128x64 out/wave), 2-barrier K-tile
// (round-4 schedule, FROZEN). Counted vmcnt(6) gates; XOR bank-swizzle both
// sides (rule #21); LGKM0+sched_barrier(0) pin before W1's BAR (rule #18).
// ---------------------------------------------------------------------------
#define TBM 256
#define TBN 256
#define TBK 64
#define NKT (DD / TBK)  // 32 K-tiles, 16 iterations of 2

__device__ __forceinline__ void async16(const u16* g, u16* l) {
  __builtin_amdgcn_global_load_lds(
      (const __attribute__((address_space(1))) unsigned int*)g,
      (__attribute__((address_space(3))) unsigned int*)l, 16, 0, 0);
}

// HF: 0=A.h0 1=A.h1 2=B.h0 3=B.h1 (compile-time); TAU_ = K-tile index.
#define STAGE(HF, TAU_)                                                      \
  do {                                                                       \
    const u16* g_ = ((HF) < 2 ? Abase : Bbase) +                             \
                    (size_t)(((HF)&1) * 128 + rr) * DD + ((TAU_) << 6) +     \
                    scol;                                                    \
    u16* l_ = ((HF) < 2 ? As : Bs) + ((TAU_)&1) * (TBM * TBK) +              \
              (((HF)&1) * 128) * TBK + t * 8;                                \
    async16(g_, l_);                                                         \
    async16(g_ + (size_t)64 * DD, l_ + 4096);                                \
  } while (0)

// Load one A m-quadrant (4 mreps x 2 ksubs = 8 x ds_read_b128) into DST.
#define LDA(DST, DB, MQ)                                                     \
  do {                                                                       \
    const u16* p_ = As + (DB) * (TBM * TBK) + (wm + (MQ)*64 + fr) * TBK;     \
    _Pragma("unroll") for (int i_ = 0; i_ < 4; ++i_) {                       \
      DST[i_][0] = *(const bf16x8*)(p_ + i_ * (16 * TBK) + c0);              \
      DST[i_][1] = *(const bf16x8*)(p_ + i_ * (16 * TBK) + c1);              \
    }                                                                        \
  } while (0)

// Load one B n-quadrant (2 nreps x 2 ksubs = 4 x ds_read_b128) into bq.
#define LDBQ(DB, NQ)                                                         \
  do {                                                                       \
    const u16* p_ = Bs + (DB) * (TBN * TBK) + (wn + (NQ)*32 + fr) * TBK;     \
    _Pragma("unroll") for (int j_ = 0; j_ < 2; ++j_) {                       \
      bq[j_][0] = *(const bf16x8*)(p_ + j_ * (16 * TBK) + c0);               \
      bq[j_][1] = *(const bf16x8*)(p_ + j_ * (16 * TBK) + c1);               \
    }                                                                        \
  } while (0)

// C-quadrant MFMA over i-range [IB,IE) x 2 nreps x 2 chained ksubs.
#define MFMAQ_R(AF, MQ, NQ, IB, IE)                                          \
  do {                                                                       \
    _Pragma("unroll") for (int i_ = (IB); i_ < (IE); ++i_)                   \
        _Pragma("unroll") for (int j_ = 0; j_ < 2; ++j_) {                   \
      f32x4 a_ = acc[(MQ)*4 + i_][(NQ)*2 + j_];                              \
      a_ = __builtin_amdgcn_mfma_f32_16x16x32_bf16(AF[i_][0], bq[j_][0], a_, \
                                                   0, 0, 0);                 \
      a_ = __builtin_amdgcn_mfma_f32_16x16x32_bf16(AF[i_][1], bq[j_][1], a_, \
                                                   0, 0, 0);                 \
      acc[(MQ)*4 + i_][(NQ)*2 + j_] = a_;                                    \
    }                                                                        \
  } while (0)

#define MFMAQ(AF, MQ, NQ) MFMAQ_R(AF, MQ, NQ, 0, 4)

#define BAR __builtin_amdgcn_s_barrier()
#define LGKM0 asm volatile("s_waitcnt lgkmcnt(0)")
#define LGKM8 asm volatile("s_waitcnt lgkmcnt(8)")
#define LGKM12 asm volatile("s_waitcnt lgkmcnt(12)")
#define SCHED0 __builtin_amdgcn_sched_barrier(0)
#define PRIO1 __builtin_amdgcn_s_setprio(1)
#define PRIO0 __builtin_amdgcn_s_setprio(0)

__global__ __launch_bounds__(512, 2) void encode_gemm(
    const u16* __restrict__ Xh,   // [rows,2048] (pre-offset to chunk)
    const u16* __restrict__ Wh,   // [16384,2048]
    const float* __restrict__ benc,
    float* __restrict__ Z) {      // [rows,16384]
  __shared__ u16 As[2 * TBM * TBK];  // 64 KB (2 dbuf x 256 x 64)
  __shared__ u16 Bs[2 * TBN * TBK];  // 64 KB
  int t = threadIdx.x;
  int m0 = blockIdx.y * TBM;
  int n0 = blockIdx.x * TBN;

  int lane = t & 63, w = t >> 6;
  int wm = (w & 1) * 128;   // wave M offset (2 waves in M)
  int wn = (w >> 1) * 64;   // wave N offset (4 waves in N)
  int fr = lane & 15;
  int fq = lane >> 4;
  // swizzled ds_read column granules (elements), ksub 0 / ksub 1
  int c0 = ((fq ^ (fr & 7)) << 3);
  int c1 = (((4 + fq) ^ (fr & 7)) << 3);
  // staging: thread t covers row rr (per q: +0/+64), slot t&7, swizzled src
  int rr = t >> 3;
  int scol = (((t & 7) ^ (rr & 7)) << 3);

  const u16* Abase = Xh + (size_t)m0 * DD;
  const u16* Bbase = Wh + (size_t)n0 * DD;

  f32x4 acc[8][4] = {};
  bf16x8 af0[4][2], af1[4][2], bq[2][2];

  // ---- prologue: stage tile0 (4 halves) + tile1 {Ah0,Ah1,Bh0} ----
  STAGE(0, 0); STAGE(1, 0); STAGE(2, 0); STAGE(3, 0);
  asm volatile("s_waitcnt vmcnt(4)" ::: "memory");
  STAGE(0, 1); STAGE(1, 1); STAGE(2, 1);
  asm volatile("s_waitcnt vmcnt(6)" ::: "memory");  // tile0 fully landed
  BAR;

  for (int it = 0; it < NKT / 2; ++it) {
    const int notlast = (it < NKT / 2 - 1);
    // ================= tile 2it (buf0) =================
    // W1: all reads + stair; reload bq<-NQ1 after Q00/Q10; LGKM0 pin; BAR
    LDBQ(0, 0);
    LDA(af0, 0, 0);
    LDA(af1, 0, 1);
    STAGE(3, 2 * it + 1);
    LGKM12; PRIO1; MFMAQ_R(af0, 0, 0, 0, 2);
    LGKM8;  MFMAQ_R(af0, 0, 0, 2, 4);
    LGKM0;  MFMAQ(af1, 1, 0); PRIO0;
    LDBQ(0, 1);
    LGKM0; SCHED0; BAR;
    // W2: stage next-next tile into buf0 (all reads retired); reg-only MFMA
    if (notlast) { STAGE(0, 2 * it + 2); STAGE(1, 2 * it + 2); STAGE(2, 2 * it + 2); }
    PRIO1; MFMAQ(af0, 0, 1); MFMAQ(af1, 1, 1); PRIO0;
    if (notlast) asm volatile("s_waitcnt vmcnt(6)" ::: "memory");
    else         asm volatile("s_waitcnt vmcnt(0)" ::: "memory");
    BAR;  // tile 2it+1 fully landed in buf1
    // ================= tile 2it+1 (buf1) =================
    LDBQ(1, 0);
    LDA(af0, 1, 0);
    LDA(af1, 1, 1);
    if (notlast) STAGE(3, 2 * it + 2);
    LGKM12; PRIO1; MFMAQ_R(af0, 0, 0, 0, 2);
    LGKM8;  MFMAQ_R(af0, 0, 0, 2, 4);
    LGKM0;  MFMAQ(af1, 1, 0); PRIO0;
    LDBQ(1, 1);
    LGKM0; SCHED0; BAR;
    if (notlast) { STAGE(0, 2 * it + 3); STAGE(1, 2 * it + 3); STAGE(2, 2 * it + 3); }
    PRIO1; MFMAQ(af0, 0, 1); MFMAQ(af1, 1, 1); PRIO0;
    if (notlast) asm volatile("s_waitcnt vmcnt(6)" ::: "memory");
    BAR;  // tile 2it+2 fully landed in buf0
  }

  // ---- epilogue: C/D layout col = lane&15, row = (lane>>4)*4 + reg ----
  int rbase = m0 + wm + fq * 4;
#pragma unroll
  for (int nr = 0; nr < 4; ++nr) {
    int col = n0 + wn + nr * 16 + fr;
    float be = benc[col];
#pragma unroll
    for (int mr = 0; mr < 8; ++mr) {
      int row = rbase + mr * 16;
#pragma unroll
      for (int r = 0; r < 4; ++r)
        Z[(size_t)(row + r) * LL + col] = acc[mr][nr][r] + be;
    }
  }
}

// ---------------------------------------------------------------------------
// Kernel 4 (FUSED topk+fixup): per-row top-64 classify on |zhat|.
// FAST-PATH selection (this round): one filter pass pushes keys >= 2.0f
// (|z| bit key >= 0x40000000) into an LDS list; wave 0 alone runs the same
// 15-round radix over the list with intra-wave shfl only — ZERO block
// barriers (was 15). Equivalence: if ncand >= KT the full radix sets bit 30
// in round 1 (count(>=2.0) = ncand >= KT), so cut >= 2.0 and all subsequent
// counts over the full set equal counts over the list -> bit-identical cut.
// ncand < KT or list overflow (> CCAP) -> fallback to the original
// block-wide radix (kept verbatim). Downstream TAU window / scatter / fixup
// unchanged; tier-3 reads contiguous Wt rows.
// ---------------------------------------------------------------------------
__global__ __launch_bounds__(512) void topkfix_kernel(
    const float* __restrict__ Z, const float* __restrict__ X32,
    const float* __restrict__ benc, const u16* __restrict__ Wh,
    const u16* __restrict__ Wl, const float* __restrict__ Wt,
    float* __restrict__ ZS, int* __restrict__ TKI, float* __restrict__ TKV,
    int r0) {
  int lrow = blockIdx.x, grow = r0 + lrow, t = threadIdx.x;
  const float* zr = Z + (size_t)lrow * LL;
  float* zs = ZS + (size_t)lrow * LL;

  __shared__ unsigned cand[CCAP];
  __shared__ unsigned ncand, nsel, ntie, cutsh;
  __shared__ int red[2][8];
  __shared__ int widx[WCAP];

  if (t == 0) { ncand = 0; nsel = 0; ntie = 0; }
  __syncthreads();

  // ---- load keys + zero zs ----
  uint4 kv[8];  // |zhat| bit keys, 32 per thread
#pragma unroll
  for (int i = 0; i < 8; ++i) {
    float4 v = ((const float4*)zr)[t + i * 512];
    kv[i].x = __float_as_uint(v.x) & 0x7fffffffu;
    kv[i].y = __float_as_uint(v.y) & 0x7fffffffu;
    kv[i].z = __float_as_uint(v.z) & 0x7fffffffu;
    kv[i].w = __float_as_uint(v.w) & 0x7fffffffu;
  }
  float4 z4 = {0.f, 0.f, 0.f, 0.f};
#pragma unroll
  for (int i = 0; i < 8; ++i) ((float4*)zs)[t + i * 512] = z4;

  // ---- filter pass: push keys >= 2.0 ----
  const unsigned thrKey = 0x40000000u;  // __float_as_uint(2.0f)
#pragma unroll
  for (int i = 0; i < 8; ++i) {
    unsigned k4[4] = {kv[i].x, kv[i].y, kv[i].z, kv[i].w};
#pragma unroll
    for (int q = 0; q < 4; ++q) {
      if (k4[q] >= thrKey) {
        unsigned p = atomicAdd(&ncand, 1u);
        if (p < (unsigned)CCAP) cand[p] = k4[q];
      }
    }
  }
  __syncthreads();

  unsigned cut = 0;  // prefix over bits 30..16; low 16 bits stay 0
  unsigned nc = ncand;  // uniform across block (post-barrier)
  if (nc >= (unsigned)KT && nc <= (unsigned)CCAP) {
    // fast path: single-wave radix over the candidate list
    if (t < 64) {
      unsigned c = 0;
      for (int bit = 30; bit >= 16; --bit) {
        unsigned ct = c | (1u << bit);
        int cnt = 0;
        for (int j = t; j < (int)nc; j += 64) cnt += (cand[j] >= ct) ? 1 : 0;
        for (int off = 32; off > 0; off >>= 1) cnt += __shfl_down(cnt, off, 64);
        cnt = __shfl(cnt, 0, 64);
        if (cnt >= KT) c = ct;
      }
      if (t == 0) cutsh = c;
    }
    __syncthreads();
    cut = cutsh;
  } else {
    // fallback: original block-wide radix (rare / never on this input)
    for (int bit = 30; bit >= 16; --bit) {
      int ph = bit & 1;
      unsigned ct = cut | (1u << bit);
      int cnt = 0;
#pragma unroll
      for (int i = 0; i < 8; ++i)
        cnt += (kv[i].x >= ct) + (kv[i].y >= ct) + (kv[i].z >= ct) + (kv[i].w >= ct);
      for (int off = 32; off > 0; off >>= 1) cnt += __shfl_down(cnt, off, 64);
      if ((t & 63) == 0) red[ph][t >> 6] = cnt;
      __syncthreads();
      int total = 0;
#pragma unroll
      for (int wv = 0; wv < 8; ++wv) total += red[ph][wv];
      if (total >= KT) cut = ct;
    }
  }

  float c16 = __uint_as_float(cut);
  float cnx = __uint_as_float(cut + 0x10000u);
  float chi = cnx + TAU;
  float clo = c16 - TAU; if (clo < 0.f) clo = 0.f;
  unsigned hiKey = __float_as_uint(chi);
  unsigned loKey = (clo > 0.f) ? __float_as_uint(clo) : 0u;

#pragma unroll
  for (int i = 0; i < 8; ++i) {
    int base = 4 * (t + i * 512);
    unsigned k4[4] = {kv[i].x, kv[i].y, kv[i].z, kv[i].w};
#pragma unroll
    for (int q = 0; q < 4; ++q) {
      unsigned key = k4[q];
      int idx = base + q;
      if (key > hiKey) {  // sure: count(> bucket_hi + TAU) <= 63 by invariant
        unsigned p = atomicAdd(&nsel, 1u);
        if (p < KT) {
          float v = zr[idx];
          TKI[grow * KT + p] = idx;
          TKV[grow * KT + p] = v;
          zs[idx] = v;
        }
      } else if (key >= loKey) {
        unsigned p = atomicAdd(&ntie, 1u);
        if (p < WCAP) widx[p] = idx;
      }
    }
  }
  __syncthreads();
  int ns = (int)nsel; if (ns > KT) ns = KT;
  // insurance: pre-fill deferred slots (fixup overwrites; under-coverage
  // degrades to benign zeros, not poison)
  if (t >= ns && t < KT) { TKI[grow * KT + t] = 0; TKV[grow * KT + t] = 0.f; }
  int wcnt = (int)ntie; if (wcnt > WCAP) wcnt = WCAP;
  int deferred = KT - ns;
  if (deferred <= 0) return;              // uniform exit
  if (deferred > wcnt) deferred = wcnt;   // safety (tau violation; soft)

  // ---- phase 2: fixup from LDS-resident window ----
  if (wcnt == deferred) {  // uncontested: take all (zhat values)
    if (t < wcnt) {
      int idx = widx[t];
      float v = zr[idx];
      TKI[grow * KT + ns + t] = idx;
      TKV[grow * KT + ns + t] = v;
      zs[idx] = v;
    }
    return;
  }

  // contested: mid-tier recompute, one candidate per wave, vectorized
  int wid = t >> 6, ln = t & 63;
  __shared__ float xs[DD];
  __shared__ double wz[WCAP];
  __shared__ int exact_flag[WCAP];
  for (int i = t; i < DD; i += 512) xs[i] = X32[(size_t)grow * DD + i];
  __syncthreads();
  for (int j = wid; j < wcnt; j += 8) {
    int idx = widx[j];
    const u16* wh = Wh + (size_t)idx * DD;
    const u16* wl = Wl + (size_t)idx * DD;
    double p = 0.0;
#pragma unroll
    for (int kb = 0; kb < 8; ++kb) {
      int k = kb * 256 + ln * 4;
      u16x4 h4 = *(const u16x4*)(wh + k);
      u16x4 l4 = *(const u16x4*)(wl + k);
      f32x4 x4 = *(const f32x4*)(xs + k);
#pragma unroll
      for (int e = 0; e < 4; ++e)
        p += (double)x4[e] * ((double)bf2f(h4[e]) + (double)bf2f(l4[e]));
    }
    for (int off = 32; off > 0; off >>= 1) p += __shfl_down(p, off, 64);
    if (ln == 0) wz[j] = p + (double)benc[idx];
  }
  __syncthreads();

  // tier-3 marking: boundary = deferred-th largest |wz|; flag near-boundary
  if (t == 0) {
    int taken = 0;
    double b = 0.0;
    for (int s = 0; s < deferred; ++s) {
      int best = -1; double bv = -1.0;
      for (int j = 0; j < wcnt; ++j) {
        if (taken & (1 << j)) continue;
        double a = fabs(wz[j]);
        if (best < 0 || a > bv || (a == bv && widx[j] < widx[best])) { best = j; bv = a; }
      }
      taken |= (1 << best);
      b = bv;
    }
    for (int j = 0; j < wcnt; ++j)
      exact_flag[j] = (fabs(fabs(wz[j]) - b) < (double)T3) ? 1 : 0;
  }
  __syncthreads();
  // tier-3 exact fp64: wave-parallel, CONTIGUOUS Wt row (same element order
  // per lane as the old W-column read -> bitwise-identical result)
  for (int j = wid; j < wcnt; j += 8) {
    if (!exact_flag[j]) continue;  // uniform per wave (shared flag)
    int idx = widx[j];
    const float* wrow = Wt + (size_t)idx * DD;
    double p = 0.0;
#pragma unroll 4
    for (int k = ln; k < DD; k += 64)
      p += (double)xs[k] * (double)wrow[k];
    for (int off = 32; off > 0; off >>= 1) p += __shfl_down(p, off, 64);
    if (ln == 0) wz[j] = p + (double)benc[idx];
  }
  __syncthreads();

  if (t == 0) {
    int taken = 0;
    for (int s = 0; s < deferred; ++s) {
      int best = -1; double bv = -1.0;
      for (int j = 0; j < wcnt; ++j) {
        if (taken & (1 << j)) continue;
        double a = fabs(wz[j]);
        if (best < 0 || a > bv || (a == bv && widx[j] < widx[best])) { best = j; bv = a; }
      }
      taken |= (1 << best);
      int idx = widx[best];
      float v = (float)wz[best];
      TKI[grow * KT + ns + s] = idx;
      TKV[grow * KT + ns + s] = v;
      zs[idx] = v;
    }
  }
}

// ---------------------------------------------------------------------------
// Kernel 6: decode  recon[b,d] = b_dec[d] + sum_j val_j * Wh[idx_j, d]
// ---------------------------------------------------------------------------
__global__ __launch_bounds__(256) void decode_kernel(
    const u16* __restrict__ Wh, const float* __restrict__ bdec,
    const int* __restrict__ TKI, const float* __restrict__ TKV,
    float* __restrict__ OUT) {
  int row = blockIdx.x, t = threadIdx.x;
  __shared__ int sidx[KT];
  __shared__ float sval[KT];
  if (t < KT) {
    sidx[t] = TKI[row * KT + t] & (LL - 1);
    sval[t] = TKV[row * KT + t];
  }
  __syncthreads();
  int d0 = t * 8;
  float acc[8] = {0.f, 0.f, 0.f, 0.f, 0.f, 0.f, 0.f, 0.f};
#pragma unroll 8
  for (int j = 0; j < KT; ++j) {
    const u16x8 wv = *(const u16x8*)(Wh + (size_t)sidx[j] * DD + d0);
    float v = sval[j];
#pragma unroll
    for (int e = 0; e < 8; ++e) acc[e] = fmaf(v, bf2f(wv[e]), acc[e]);
  }
  float4 o0, o1;
  o0.x = acc[0] + bdec[d0 + 0]; o0.y = acc[1] + bdec[d0 + 1];
  o0.z = acc[2] + bdec[d0 + 2]; o0.w = acc[3] + bdec[d0 + 3];
  o1.x = acc[4] + bdec[d0 + 4]; o1.y = acc[5] + bdec[d0 + 5];
  o1.z = acc[6] + bdec[d0 + 6]; o1.w = acc[7] + bdec[d0 + 7];
  float* dst = OUT + (size_t)row * DD + d0;
  *(float4*)dst = o0;
  *(float4*)(dst + 4) = o1;
}

// ---------------------------------------------------------------------------
// ws layout (~1.2 GB available per round-4 fillBuffer evidence):
//  [Xh 16M][Wh 64M][Wl 64M][Wt 128M][TKI 1M][TKV 1M][Zc ...(268M @ 1 chunk)]
// ---------------------------------------------------------------------------
extern "C" void kernel_launch(void* const* d_in, const int* in_sizes, int n_in,
                              void* d_out, int out_size, void* d_ws,
                              size_t ws_size, hipStream_t stream) {
  const float* X = (const float*)d_in[0];     // [4096, 2048] fp32
  const float* W = (const float*)d_in[1];     // [2048, 16384] fp32
  const float* benc = (const float*)d_in[2];  // [16384] fp32
  const float* bdec = (const float*)d_in[3];  // [2048] fp32

  char* ws = (char*)d_ws;
  const size_t XH_B = (size_t)NB * DD * 2;      // 16,777,216
  const size_t WH_B = (size_t)LL * DD * 2;      // 67,108,864
  const size_t WT_B = (size_t)LL * DD * 4;      // 134,217,728
  const size_t TKI_B = (size_t)NB * KT * 4;     // 1,048,576
  u16* Xh = (u16*)ws;
  u16* Wh = (u16*)(ws + XH_B);
  u16* Wl = (u16*)(ws + XH_B + WH_B);
  float* Wt = (float*)(ws + XH_B + 2 * WH_B);
  int* TKI = (int*)(ws + XH_B + 2 * WH_B + WT_B);
  float* TKV = (float*)(ws + XH_B + 2 * WH_B + WT_B + TKI_B);
  float* Zc = (float*)(ws + XH_B + 2 * WH_B + WT_B + 2 * TKI_B);

  size_t fixed = XH_B + 2 * WH_B + WT_B + 2 * TKI_B;
  size_t avail = (ws_size > fixed) ? (ws_size - fixed) : 0;
  int chunk = (int)(avail / ((size_t)LL * 4));
  chunk = (chunk / TBM) * TBM;
  if (chunk > NB) chunk = NB;
  if (chunk < TBM) chunk = TBM;

  float* out_recon = (float*)d_out;                    // [4096, 2048]
  float* out_zs = (float*)d_out + (size_t)NB * DD;     // [4096, 16384]

  prep_x<<<NB * DD / 1024, 256, 0, stream>>>(X, Xh);
  prep_w<<<dim3(LL / 64, DD / 64), 256, 0, stream>>>(W, Wh, Wl, Wt);
  for (int r0 = 0; r0 < NB; r0 += chunk) {
    int rows = NB - r0; if (rows > chunk) rows = chunk;
    encode_gemm<<<dim3(LL / TBN, rows / TBM), 512, 0, stream>>>(
        Xh + (size_t)r0 * DD, Wh, benc, Zc);
    topkfix_kernel<<<rows, 512, 0, stream>>>(
        Zc, X, benc, Wh, Wl, Wt, out_zs + (size_t)r0 * LL, TKI, TKV, r0);
  }
  decode_kernel<<<NB, 256, 0, stream>>>(Wh, bdec, TKI, TKV, out_recon);
}

// Round 9
// 1119.228 us; speedup vs baseline: 1.0696x; 1.0696x over previous
//
#include <hip/hip_runtime.h>
#include <stdint.h>

// Problem constants (B, D, L, K from the reference). fp32 I/O per reference.
#define NB 4096
#define DD 2048
#define LL 16384
#define KT 64
#define WCAP 24        // window candidate cap per row
#define TAU 1.2e-2f    // sure/window margin: 5.7 sigma of zhat error (hh-only)

typedef unsigned short u16;
typedef __bf16 bf16x8 __attribute__((ext_vector_type(8)));
typedef float f32x4 __attribute__((ext_vector_type(4)));
typedef unsigned short u16x4 __attribute__((ext_vector_type(4)));
typedef unsigned short u16x8 __attribute__((ext_vector_type(8)));

__device__ __forceinline__ float bf2f(u16 b) {
  return __uint_as_float(((unsigned)b) << 16);
}
__device__ __forceinline__ u16 f2bf(float f) {
  unsigned u = __float_as_uint(f);
  unsigned r = u + 0x7fffu + ((u >> 16) & 1u);  // RNE
  return (u16)(r >> 16);
}

// ---------------------------------------------------------------------------
// Kernel 1: X fp32 -> Xh bf16 (hi part only; fixup reads fp32 X directly)
// ---------------------------------------------------------------------------
__global__ __launch_bounds__(256) void prep_x(const float* __restrict__ X,
                                              u16* __restrict__ Xh) {
  int i = (blockIdx.x * 256 + threadIdx.x) * 4;
  float4 v = *(const float4*)(X + i);
  u16x4 h;
  h[0] = f2bf(v.x); h[1] = f2bf(v.y); h[2] = f2bf(v.z); h[3] = f2bf(v.w);
  *(u16x4*)(Xh + i) = h;
}

// ---------------------------------------------------------------------------
// Kernel 2: transpose W fp32 [2048,16384] -> Wh bf16 [16384,2048] (GEMM +
// decode) and Wt fp32 [16384,2048] (exact fixup dots). Wl dropped: the
// unified exact-fp64 fixup makes the bf16-split mid-tier redundant
// (-64 MB of writes).
// ---------------------------------------------------------------------------
__global__ __launch_bounds__(256) void prep_w(const float* __restrict__ W,
                                              u16* __restrict__ Wh,
                                              float* __restrict__ Wt) {
  __shared__ float tile[64][65];  // +1 pad breaks write-phase bank aliasing
  int l0 = blockIdx.x * 64, d0 = blockIdx.y * 64;
  int t = threadIdx.x;
  int lx = (t & 15) * 4;
  int dq = t >> 4;
#pragma unroll
  for (int p = 0; p < 4; ++p) {
    int d = dq + p * 16;
    float4 v = *(const float4*)(W + (size_t)(d0 + d) * LL + l0 + lx);
    tile[d][lx + 0] = v.x; tile[d][lx + 1] = v.y;
    tile[d][lx + 2] = v.z; tile[d][lx + 3] = v.w;
  }
  __syncthreads();
  int dx = (t & 15) * 4;
  int lq = t >> 4;
#pragma unroll
  for (int p = 0; p < 4; ++p) {
    int l = lq + p * 16;
    u16x4 h;
    float4 wv;
#pragma unroll
    for (int q = 0; q < 4; ++q) {
      float w = tile[dx + q][l];
      h[q] = f2bf(w);
      ((float*)&wv)[q] = w;
    }
    size_t o = (size_t)(l0 + l) * DD + d0 + dx;
    *(u16x4*)(Wh + o) = h;
    *(float4*)(Wt + o) = wv;
  }
}

// ---------------------------------------------------------------------------
// Kernel 3: encode GEMM  zhat = Xh·Wh^T + benc
// RESTORED to the round-2 7-barrier read-ahead schedule — the only variant
// actually MEASURED in a top-5 (283-288 us across rounds 1-3). The 2-barrier
// rewrite was never observed (hidden below larger kernels) and is a
// suspected regression (m196: removing the fine interleave can hurt).
// ---------------------------------------------------------------------------
#define TBM 256
#define TBN 256
#define TBK 64
#define NKT (DD / TBK)  // 32 K-tiles, 16 iterations of 2

__device__ __forceinline__ void async16(const u16* g, u16* l) {
  __builtin_amdgcn_global_load_lds(
      (const __attribute__((address_space(1))) unsigned int*)g,
      (__attribute__((address_space(3))) unsigned int*)l, 16, 0, 0);
}

// HF: 0=A.h0 1=A.h1 2=B.h0 3=B.h1 (compile-time); TAU_ = K-tile index.
#define STAGE(HF, TAU_)                                                      \
  do {                                                                       \
    const u16* g_ = ((HF) < 2 ? Abase : Bbase) +                             \
                    (size_t)(((HF)&1) * 128 + rr) * DD + ((TAU_) << 6) +     \
                    scol;                                                    \
    u16* l_ = ((HF) < 2 ? As : Bs) + ((TAU_)&1) * (TBM * TBK) +              \
              (((HF)&1) * 128) * TBK + t * 8;                                \
    async16(g_, l_);                                                         \
    async16(g_ + (size_t)64 * DD, l_ + 4096);                                \
  } while (0)

// Load one A m-quadrant (4 mreps x 2 ksubs = 8 x ds_read_b128) into DST.
#define LDA(DST, DB, MQ)                                                     \
  do {                                                                       \
    const u16* p_ = As + (DB) * (TBM * TBK) + (wm + (MQ)*64 + fr) * TBK;     \
    _Pragma("unroll") for (int i_ = 0; i_ < 4; ++i_) {                       \
      DST[i_][0] = *(const bf16x8*)(p_ + i_ * (16 * TBK) + c0);              \
      DST[i_][1] = *(const bf16x8*)(p_ + i_ * (16 * TBK) + c1);              \
    }                                                                        \
  } while (0)

// Load one B n-quadrant (2 nreps x 2 ksubs = 4 x ds_read_b128) into bq.
#define LDBQ(DB, NQ)                                                         \
  do {                                                                       \
    const u16* p_ = Bs + (DB) * (TBN * TBK) + (wn + (NQ)*32 + fr) * TBK;     \
    _Pragma("unroll") for (int j_ = 0; j_ < 2; ++j_) {                       \
      bq[j_][0] = *(const bf16x8*)(p_ + j_ * (16 * TBK) + c0);               \
      bq[j_][1] = *(const bf16x8*)(p_ + j_ * (16 * TBK) + c1);               \
    }                                                                        \
  } while (0)

// One C-quadrant x K=64: 4x2 frags x 2 chained ksubs = 16 MFMA.
#define MFMAQ(AF, MQ, NQ)                                                    \
  do {                                                                       \
    _Pragma("unroll") for (int i_ = 0; i_ < 4; ++i_)                         \
        _Pragma("unroll") for (int j_ = 0; j_ < 2; ++j_) {                   \
      f32x4 a_ = acc[(MQ)*4 + i_][(NQ)*2 + j_];                              \
      a_ = __builtin_amdgcn_mfma_f32_16x16x32_bf16(AF[i_][0], bq[j_][0], a_, \
                                                   0, 0, 0);                 \
      a_ = __builtin_amdgcn_mfma_f32_16x16x32_bf16(AF[i_][1], bq[j_][1], a_, \
                                                   0, 0, 0);                 \
      acc[(MQ)*4 + i_][(NQ)*2 + j_] = a_;                                    \
    }                                                                        \
  } while (0)

#define BAR __builtin_amdgcn_s_barrier()
#define LGKM0 asm volatile("s_waitcnt lgkmcnt(0)")
#define LGKM8 asm volatile("s_waitcnt lgkmcnt(8)")
#define PRIO1 __builtin_amdgcn_s_setprio(1)
#define PRIO0 __builtin_amdgcn_s_setprio(0)

__global__ __launch_bounds__(512, 2) void encode_gemm(
    const u16* __restrict__ Xh,   // [rows,2048] (pre-offset to chunk)
    const u16* __restrict__ Wh,   // [16384,2048]
    const float* __restrict__ benc,
    float* __restrict__ Z) {      // [rows,16384]
  __shared__ u16 As[2 * TBM * TBK];  // 64 KB (2 dbuf x 256 x 64)
  __shared__ u16 Bs[2 * TBN * TBK];  // 64 KB
  int t = threadIdx.x;
  int m0 = blockIdx.y * TBM;
  int n0 = blockIdx.x * TBN;

  int lane = t & 63, w = t >> 6;
  int wm = (w & 1) * 128;   // wave M offset (2 waves in M)
  int wn = (w >> 1) * 64;   // wave N offset (4 waves in N)
  int fr = lane & 15;
  int fq = lane >> 4;
  // swizzled ds_read column granules (elements), ksub 0 / ksub 1
  int c0 = ((fq ^ (fr & 7)) << 3);
  int c1 = (((4 + fq) ^ (fr & 7)) << 3);
  // staging: thread t covers row rr (per q: +0/+64), slot t&7, swizzled src
  int rr = t >> 3;
  int scol = (((t & 7) ^ (rr & 7)) << 3);

  const u16* Abase = Xh + (size_t)m0 * DD;
  const u16* Bbase = Wh + (size_t)n0 * DD;

  f32x4 acc[8][4] = {};
  bf16x8 af0[4][2], af1[4][2], bq[2][2];

  // ---- prologue: stage tile0 (4 halves) + tile1 {Ah0,Ah1,Bh0} ----
  STAGE(0, 0); STAGE(1, 0); STAGE(2, 0); STAGE(3, 0);
  asm volatile("s_waitcnt vmcnt(4)" ::: "memory");
  STAGE(0, 1); STAGE(1, 1); STAGE(2, 1);
  asm volatile("s_waitcnt vmcnt(6)" ::: "memory");  // tile0 fully landed
  BAR;

  for (int it = 0; it < NKT / 2; ++it) {
    const int notlast = (it < NKT / 2 - 1);
    // ================= tile 2it (buf0) =================
    // Pa: ALL A reads + bq<-NQ0 (20 ds_reads); stage [2it+1].Bh1.
    // lgkm(8): af0+bq ready, af1 still in flight under Q00's MFMA.
    LDA(af0, 0, 0);
    LDBQ(0, 0);
    LDA(af1, 0, 1);
    STAGE(3, 2 * it + 1);
    BAR; LGKM8; PRIO1; MFMAQ(af0, 0, 0); PRIO0; BAR;
    // Pb: af1 ready; Q10; reload bq<-NQ1 AFTER the MFMA.
    LGKM0; PRIO1; MFMAQ(af1, 1, 0); PRIO0;
    LDBQ(0, 1);
    BAR;
    // Pc: stage [2it+2].Ah0 (A reads completed cross-wave at Pb's BAR)
    if (notlast) STAGE(0, 2 * it + 2);
    BAR; LGKM0; PRIO1; MFMAQ(af0, 0, 1); PRIO0; BAR;
    // Pd: stage [2it+2].{Ah1,Bh0}; reg-only Q11; counted vmcnt gate
    if (notlast) { STAGE(1, 2 * it + 2); STAGE(2, 2 * it + 2); }
    BAR; PRIO1; MFMAQ(af1, 1, 1); PRIO0;
    if (notlast) asm volatile("s_waitcnt vmcnt(6)" ::: "memory");
    else         asm volatile("s_waitcnt vmcnt(0)" ::: "memory");
    BAR;  // tile 2it+1 fully landed in buf1
    // ================= tile 2it+1 (buf1) =================
    LDA(af0, 1, 0);
    LDBQ(1, 0);
    LDA(af1, 1, 1);
    if (notlast) STAGE(3, 2 * it + 2);
    BAR; LGKM8; PRIO1; MFMAQ(af0, 0, 0); PRIO0; BAR;
    LGKM0; PRIO1; MFMAQ(af1, 1, 0); PRIO0;
    LDBQ(1, 1);
    BAR;
    if (notlast) STAGE(0, 2 * it + 3);
    BAR; LGKM0; PRIO1; MFMAQ(af0, 0, 1); PRIO0; BAR;
    if (notlast) { STAGE(1, 2 * it + 3); STAGE(2, 2 * it + 3); }
    BAR; PRIO1; MFMAQ(af1, 1, 1); PRIO0;
    if (notlast) asm volatile("s_waitcnt vmcnt(6)" ::: "memory");
    BAR;  // tile 2it+2 fully landed in buf0
  }

  // ---- epilogue: C/D layout col = lane&15, row = (lane>>4)*4 + reg ----
  int rbase = m0 + wm + fq * 4;
#pragma unroll
  for (int nr = 0; nr < 4; ++nr) {
    int col = n0 + wn + nr * 16 + fr;
    float be = benc[col];
#pragma unroll
    for (int mr = 0; mr < 8; ++mr) {
      int row = rbase + mr * 16;
#pragma unroll
      for (int r = 0; r < 4; ++r)
        Z[(size_t)(row + r) * LL + col] = acc[mr][nr][r] + be;
    }
  }
}

// ---------------------------------------------------------------------------
// Kernel 4 (FUSED topk+fixup): per-row top-64 classify on |zhat| — block-wide
// 15-round radix (round-7 form, measured 382; the wave-0 fast path was a
// measured regression and is reverted). Fixup: UNIFIED exact-fp64 dots from
// contiguous fp32 Wt rows for all contested candidates (one pass; replaces
// bf16-split mid-tier + tier-3 second pass — same bytes, fewer barriers,
// no bf2f VALU; wz error ~1e-13, selection ordering = old tier-3's).
// ---------------------------------------------------------------------------
__global__ __launch_bounds__(512) void topkfix_kernel(
    const float* __restrict__ Z, const float* __restrict__ X32,
    const float* __restrict__ benc, const float* __restrict__ Wt,
    float* __restrict__ ZS, int* __restrict__ TKI, float* __restrict__ TKV,
    int r0) {
  int lrow = blockIdx.x, grow = r0 + lrow, t = threadIdx.x;
  const float* zr = Z + (size_t)lrow * LL;
  float* zs = ZS + (size_t)lrow * LL;

  uint4 kv[8];  // |zhat| bit keys, 32 per thread
#pragma unroll
  for (int i = 0; i < 8; ++i) {
    float4 v = ((const float4*)zr)[t + i * 512];
    kv[i].x = __float_as_uint(v.x) & 0x7fffffffu;
    kv[i].y = __float_as_uint(v.y) & 0x7fffffffu;
    kv[i].z = __float_as_uint(v.z) & 0x7fffffffu;
    kv[i].w = __float_as_uint(v.w) & 0x7fffffffu;
  }
  float4 z4 = {0.f, 0.f, 0.f, 0.f};
#pragma unroll
  for (int i = 0; i < 8; ++i) ((float4*)zs)[t + i * 512] = z4;

  __shared__ int red[2][8];
  unsigned cut = 0;  // prefix over bits 30..16; low 16 bits stay 0
  for (int bit = 30; bit >= 16; --bit) {
    int ph = bit & 1;
    unsigned ct = cut | (1u << bit);
    int cnt = 0;
#pragma unroll
    for (int i = 0; i < 8; ++i)
      cnt += (kv[i].x >= ct) + (kv[i].y >= ct) + (kv[i].z >= ct) + (kv[i].w >= ct);
    for (int off = 32; off > 0; off >>= 1) cnt += __shfl_down(cnt, off, 64);
    if ((t & 63) == 0) red[ph][t >> 6] = cnt;
    __syncthreads();
    int total = 0;
#pragma unroll
    for (int wv = 0; wv < 8; ++wv) total += red[ph][wv];
    if (total >= KT) cut = ct;
  }

  float c16 = __uint_as_float(cut);
  float cnx = __uint_as_float(cut + 0x10000u);
  float chi = cnx + TAU;
  float clo = c16 - TAU; if (clo < 0.f) clo = 0.f;
  unsigned hiKey = __float_as_uint(chi);
  unsigned loKey = (clo > 0.f) ? __float_as_uint(clo) : 0u;

  __shared__ unsigned nsel, ntie;
  __shared__ int widx[WCAP];
  if (t == 0) { nsel = 0; ntie = 0; }
  __syncthreads();

#pragma unroll
  for (int i = 0; i < 8; ++i) {
    int base = 4 * (t + i * 512);
    unsigned k4[4] = {kv[i].x, kv[i].y, kv[i].z, kv[i].w};
#pragma unroll
    for (int q = 0; q < 4; ++q) {
      unsigned key = k4[q];
      int idx = base + q;
      if (key > hiKey) {  // sure: count(> bucket_hi + TAU) <= 63 by invariant
        unsigned p = atomicAdd(&nsel, 1u);
        if (p < KT) {
          float v = zr[idx];
          TKI[grow * KT + p] = idx;
          TKV[grow * KT + p] = v;
          zs[idx] = v;
        }
      } else if (key >= loKey) {
        unsigned p = atomicAdd(&ntie, 1u);
        if (p < WCAP) widx[p] = idx;
      }
    }
  }
  __syncthreads();
  int ns = (int)nsel; if (ns > KT) ns = KT;
  // insurance: pre-fill deferred slots (fixup overwrites; under-coverage
  // degrades to benign zeros, not poison)
  if (t >= ns && t < KT) { TKI[grow * KT + t] = 0; TKV[grow * KT + t] = 0.f; }
  int wcnt = (int)ntie; if (wcnt > WCAP) wcnt = WCAP;
  int deferred = KT - ns;
  if (deferred <= 0) return;              // uniform exit
  if (deferred > wcnt) deferred = wcnt;   // safety (tau violation; soft)

  // ---- phase 2: fixup from LDS-resident window ----
  if (wcnt == deferred) {  // uncontested: take all (zhat values)
    if (t < wcnt) {
      int idx = widx[t];
      float v = zr[idx];
      TKI[grow * KT + ns + t] = idx;
      TKV[grow * KT + ns + t] = v;
      zs[idx] = v;
    }
    return;
  }

  // contested: exact fp64 dot from contiguous fp32 Wt rows, one candidate
  // per wave (error ~1e-13 from accumulation order only)
  int wid = t >> 6, ln = t & 63;
  __shared__ float xs[DD];
  __shared__ double wz[WCAP];
  for (int i = t; i < DD; i += 512) xs[i] = X32[(size_t)grow * DD + i];
  __syncthreads();
  for (int j = wid; j < wcnt; j += 8) {
    int idx = widx[j];
    const float* wrow = Wt + (size_t)idx * DD;
    double p = 0.0;
#pragma unroll
    for (int kb = 0; kb < 8; ++kb) {
      int k = kb * 256 + ln * 4;
      f32x4 w4 = *(const f32x4*)(wrow + k);
      f32x4 x4 = *(const f32x4*)(xs + k);
#pragma unroll
      for (int e = 0; e < 4; ++e)
        p += (double)x4[e] * (double)w4[e];
    }
    for (int off = 32; off > 0; off >>= 1) p += __shfl_down(p, off, 64);
    if (ln == 0) wz[j] = p + (double)benc[idx];
  }
  __syncthreads();

  if (t == 0) {
    int taken = 0;
    for (int s = 0; s < deferred; ++s) {
      int best = -1; double bv = -1.0;
      for (int j = 0; j < wcnt; ++j) {
        if (taken & (1 << j)) continue;
        double a = fabs(wz[j]);
        if (best < 0 || a > bv || (a == bv && widx[j] < widx[best])) { best = j; bv = a; }
      }
      taken |= (1 << best);
      int idx = widx[best];
      float v = (float)wz[best];
      TKI[grow * KT + ns + s] = idx;
      TKV[grow * KT + ns + s] = v;
      zs[idx] = v;
    }
  }
}

// ---------------------------------------------------------------------------
// Kernel 6: decode  recon[b,d] = b_dec[d] + sum_j val_j * Wh[idx_j, d]
// unroll 16: deeper outstanding-load pipeline for the L3-gather
// ---------------------------------------------------------------------------
__global__ __launch_bounds__(256) void decode_kernel(
    const u16* __restrict__ Wh, const float* __restrict__ bdec,
    const int* __restrict__ TKI, const float* __restrict__ TKV,
    float* __restrict__ OUT) {
  int row = blockIdx.x, t = threadIdx.x;
  __shared__ int sidx[KT];
  __shared__ float sval[KT];
  if (t < KT) {
    sidx[t] = TKI[row * KT + t] & (LL - 1);
    sval[t] = TKV[row * KT + t];
  }
  __syncthreads();
  int d0 = t * 8;
  float acc[8] = {0.f, 0.f, 0.f, 0.f, 0.f, 0.f, 0.f, 0.f};
#pragma unroll 16
  for (int j = 0; j < KT; ++j) {
    const u16x8 wv = *(const u16x8*)(Wh + (size_t)sidx[j] * DD + d0);
    float v = sval[j];
#pragma unroll
    for (int e = 0; e < 8; ++e) acc[e] = fmaf(v, bf2f(wv[e]), acc[e]);
  }
  float4 o0, o1;
  o0.x = acc[0] + bdec[d0 + 0]; o0.y = acc[1] + bdec[d0 + 1];
  o0.z = acc[2] + bdec[d0 + 2]; o0.w = acc[3] + bdec[d0 + 3];
  o1.x = acc[4] + bdec[d0 + 4]; o1.y = acc[5] + bdec[d0 + 5];
  o1.z = acc[6] + bdec[d0 + 6]; o1.w = acc[7] + bdec[d0 + 7];
  float* dst = OUT + (size_t)row * DD + d0;
  *(float4*)dst = o0;
  *(float4*)(dst + 4) = o1;
}

// ---------------------------------------------------------------------------
// ws layout (ws = 1152 MiB per round-4 fillBuffer WRITE_SIZE):
//  [Xh 16M][Wh 64M][Wt 128M][TKI 1M][TKV 1M][Zc 268M @ single chunk]
// ---------------------------------------------------------------------------
extern "C" void kernel_launch(void* const* d_in, const int* in_sizes, int n_in,
                              void* d_out, int out_size, void* d_ws,
                              size_t ws_size, hipStream_t stream) {
  const float* X = (const float*)d_in[0];     // [4096, 2048] fp32
  const float* W = (const float*)d_in[1];     // [2048, 16384] fp32
  const float* benc = (const float*)d_in[2];  // [16384] fp32
  const float* bdec = (const float*)d_in[3];  // [2048] fp32

  char* ws = (char*)d_ws;
  const size_t XH_B = (size_t)NB * DD * 2;      // 16,777,216
  const size_t WH_B = (size_t)LL * DD * 2;      // 67,108,864
  const size_t WT_B = (size_t)LL * DD * 4;      // 134,217,728
  const size_t TKI_B = (size_t)NB * KT * 4;     // 1,048,576
  u16* Xh = (u16*)ws;
  u16* Wh = (u16*)(ws + XH_B);
  float* Wt = (float*)(ws + XH_B + WH_B);
  int* TKI = (int*)(ws + XH_B + WH_B + WT_B);
  float* TKV = (float*)(ws + XH_B + WH_B + WT_B + TKI_B);
  float* Zc = (float*)(ws + XH_B + WH_B + WT_B + 2 * TKI_B);

  size_t fixed = XH_B + WH_B + WT_B + 2 * TKI_B;
  size_t avail = (ws_size > fixed) ? (ws_size - fixed) : 0;
  int chunk = (int)(avail / ((size_t)LL * 4));
  chunk = (chunk / TBM) * TBM;
  if (chunk > NB) chunk = NB;
  if (chunk < TBM) chunk = TBM;

  float* out_recon = (float*)d_out;                    // [4096, 2048]
  float* out_zs = (float*)d_out + (size_t)NB * DD;     // [4096, 16384]

  prep_x<<<NB * DD / 1024, 256, 0, stream>>>(X, Xh);
  prep_w<<<dim3(LL / 64, DD / 64), 256, 0, stream>>>(W, Wh, Wt);
  for (int r0 = 0; r0 < NB; r0 += chunk) {
    int rows = NB - r0; if (rows > chunk) rows = chunk;
    encode_gemm<<<dim3(LL / TBN, rows / TBM), 512, 0, stream>>>(
        Xh + (size_t)r0 * DD, Wh, benc, Zc);
    topkfix_kernel<<<rows, 512, 0, stream>>>(
        Zc, X, benc, Wt, out_zs + (size_t)r0 * LL, TKI, TKV, r0);
  }
  decode_kernel<<<NB, 256, 0, stream>>>(Wh, bdec, TKI, TKV, out_recon);
}

// Round 10
// 1074.473 us; speedup vs baseline: 1.1142x; 1.0417x over previous
//
#include <hip/hip_runtime.h>
#include <stdint.h>

// Problem constants (B, D, L, K from the reference). fp32 I/O per reference.
#define NB 4096
#define DD 2048
#define LL 16384
#define KT 64
#define WCAP 24        // window candidate cap per row
#define TAU 1.2e-2f    // sure/window margin: 5.7 sigma of zhat error (hh-only)

typedef unsigned short u16;
typedef __bf16 bf16x8 __attribute__((ext_vector_type(8)));
typedef float f32x4 __attribute__((ext_vector_type(4)));
typedef unsigned short u16x4 __attribute__((ext_vector_type(4)));
typedef unsigned short u16x8 __attribute__((ext_vector_type(8)));

__device__ __forceinline__ float bf2f(u16 b) {
  return __uint_as_float(((unsigned)b) << 16);
}
__device__ __forceinline__ u16 f2bf(float f) {
  unsigned u = __float_as_uint(f);
  unsigned r = u + 0x7fffu + ((u >> 16) & 1u);  // RNE
  return (u16)(r >> 16);
}

// ---------------------------------------------------------------------------
// Kernel 1: X fp32 -> Xh bf16 (hi part only; fixup reads fp32 X directly)
// ---------------------------------------------------------------------------
__global__ __launch_bounds__(256) void prep_x(const float* __restrict__ X,
                                              u16* __restrict__ Xh) {
  int i = (blockIdx.x * 256 + threadIdx.x) * 4;
  float4 v = *(const float4*)(X + i);
  u16x4 h;
  h[0] = f2bf(v.x); h[1] = f2bf(v.y); h[2] = f2bf(v.z); h[3] = f2bf(v.w);
  *(u16x4*)(Xh + i) = h;
}

// ---------------------------------------------------------------------------
// Kernel 2: transpose W fp32 [2048,16384] -> Wh bf16 [16384,2048] (GEMM +
// decode) and Wt fp32 [16384,2048] (exact fixup dots).
// ---------------------------------------------------------------------------
__global__ __launch_bounds__(256) void prep_w(const float* __restrict__ W,
                                              u16* __restrict__ Wh,
                                              float* __restrict__ Wt) {
  __shared__ float tile[64][65];  // +1 pad breaks write-phase bank aliasing
  int l0 = blockIdx.x * 64, d0 = blockIdx.y * 64;
  int t = threadIdx.x;
  int lx = (t & 15) * 4;
  int dq = t >> 4;
#pragma unroll
  for (int p = 0; p < 4; ++p) {
    int d = dq + p * 16;
    float4 v = *(const float4*)(W + (size_t)(d0 + d) * LL + l0 + lx);
    tile[d][lx + 0] = v.x; tile[d][lx + 1] = v.y;
    tile[d][lx + 2] = v.z; tile[d][lx + 3] = v.w;
  }
  __syncthreads();
  int dx = (t & 15) * 4;
  int lq = t >> 4;
#pragma unroll
  for (int p = 0; p < 4; ++p) {
    int l = lq + p * 16;
    u16x4 h;
    float4 wv;
#pragma unroll
    for (int q = 0; q < 4; ++q) {
      float w = tile[dx + q][l];
      h[q] = f2bf(w);
      ((float*)&wv)[q] = w;
    }
    size_t o = (size_t)(l0 + l) * DD + d0 + dx;
    *(u16x4*)(Wh + o) = h;
    *(float4*)(Wt + o) = wv;
  }
}

// ---------------------------------------------------------------------------
// Kernel 3: encode GEMM  zhat = Xh·Wh^T + benc
// Round-2 7-barrier read-ahead schedule — the measured 283-288 us variant.
// FROZEN.
// ---------------------------------------------------------------------------
#define TBM 256
#define TBN 256
#define TBK 64
#define NKT (DD / TBK)  // 32 K-tiles, 16 iterations of 2

__device__ __forceinline__ void async16(const u16* g, u16* l) {
  __builtin_amdgcn_global_load_lds(
      (const __attribute__((address_space(1))) unsigned int*)g,
      (__attribute__((address_space(3))) unsigned int*)l, 16, 0, 0);
}

// HF: 0=A.h0 1=A.h1 2=B.h0 3=B.h1 (compile-time); TAU_ = K-tile index.
#define STAGE(HF, TAU_)                                                      \
  do {                                                                       \
    const u16* g_ = ((HF) < 2 ? Abase : Bbase) +                             \
                    (size_t)(((HF)&1) * 128 + rr) * DD + ((TAU_) << 6) +     \
                    scol;                                                    \
    u16* l_ = ((HF) < 2 ? As : Bs) + ((TAU_)&1) * (TBM * TBK) +              \
              (((HF)&1) * 128) * TBK + t * 8;                                \
    async16(g_, l_);                                                         \
    async16(g_ + (size_t)64 * DD, l_ + 4096);                                \
  } while (0)

// Load one A m-quadrant (4 mreps x 2 ksubs = 8 x ds_read_b128) into DST.
#define LDA(DST, DB, MQ)                                                     \
  do {                                                                       \
    const u16* p_ = As + (DB) * (TBM * TBK) + (wm + (MQ)*64 + fr) * TBK;     \
    _Pragma("unroll") for (int i_ = 0; i_ < 4; ++i_) {                       \
      DST[i_][0] = *(const bf16x8*)(p_ + i_ * (16 * TBK) + c0);              \
      DST[i_][1] = *(const bf16x8*)(p_ + i_ * (16 * TBK) + c1);              \
    }                                                                        \
  } while (0)

// Load one B n-quadrant (2 nreps x 2 ksubs = 4 x ds_read_b128) into bq.
#define LDBQ(DB, NQ)                                                         \
  do {                                                                       \
    const u16* p_ = Bs + (DB) * (TBN * TBK) + (wn + (NQ)*32 + fr) * TBK;     \
    _Pragma("unroll") for (int j_ = 0; j_ < 2; ++j_) {                       \
      bq[j_][0] = *(const bf16x8*)(p_ + j_ * (16 * TBK) + c0);               \
      bq[j_][1] = *(const bf16x8*)(p_ + j_ * (16 * TBK) + c1);               \
    }                                                                        \
  } while (0)

// One C-quadrant x K=64: 4x2 frags x 2 chained ksubs = 16 MFMA.
#define MFMAQ(AF, MQ, NQ)                                                    \
  do {                                                                       \
    _Pragma("unroll") for (int i_ = 0; i_ < 4; ++i_)                         \
        _Pragma("unroll") for (int j_ = 0; j_ < 2; ++j_) {                   \
      f32x4 a_ = acc[(MQ)*4 + i_][(NQ)*2 + j_];                              \
      a_ = __builtin_amdgcn_mfma_f32_16x16x32_bf16(AF[i_][0], bq[j_][0], a_, \
                                                   0, 0, 0);                 \
      a_ = __builtin_amdgcn_mfma_f32_16x16x32_bf16(AF[i_][1], bq[j_][1], a_, \
                                                   0, 0, 0);                 \
      acc[(MQ)*4 + i_][(NQ)*2 + j_] = a_;                                    \
    }                                                                        \
  } while (0)

#define BAR __builtin_amdgcn_s_barrier()
#define LGKM0 asm volatile("s_waitcnt lgkmcnt(0)")
#define LGKM8 asm volatile("s_waitcnt lgkmcnt(8)")
#define PRIO1 __builtin_amdgcn_s_setprio(1)
#define PRIO0 __builtin_amdgcn_s_setprio(0)

__global__ __launch_bounds__(512, 2) void encode_gemm(
    const u16* __restrict__ Xh,   // [rows,2048] (pre-offset to chunk)
    const u16* __restrict__ Wh,   // [16384,2048]
    const float* __restrict__ benc,
    float* __restrict__ Z) {      // [rows,16384]
  __shared__ u16 As[2 * TBM * TBK];  // 64 KB (2 dbuf x 256 x 64)
  __shared__ u16 Bs[2 * TBN * TBK];  // 64 KB
  int t = threadIdx.x;
  int m0 = blockIdx.y * TBM;
  int n0 = blockIdx.x * TBN;

  int lane = t & 63, w = t >> 6;
  int wm = (w & 1) * 128;   // wave M offset (2 waves in M)
  int wn = (w >> 1) * 64;   // wave N offset (4 waves in N)
  int fr = lane & 15;
  int fq = lane >> 4;
  // swizzled ds_read column granules (elements), ksub 0 / ksub 1
  int c0 = ((fq ^ (fr & 7)) << 3);
  int c1 = (((4 + fq) ^ (fr & 7)) << 3);
  // staging: thread t covers row rr (per q: +0/+64), slot t&7, swizzled src
  int rr = t >> 3;
  int scol = (((t & 7) ^ (rr & 7)) << 3);

  const u16* Abase = Xh + (size_t)m0 * DD;
  const u16* Bbase = Wh + (size_t)n0 * DD;

  f32x4 acc[8][4] = {};
  bf16x8 af0[4][2], af1[4][2], bq[2][2];

  // ---- prologue: stage tile0 (4 halves) + tile1 {Ah0,Ah1,Bh0} ----
  STAGE(0, 0); STAGE(1, 0); STAGE(2, 0); STAGE(3, 0);
  asm volatile("s_waitcnt vmcnt(4)" ::: "memory");
  STAGE(0, 1); STAGE(1, 1); STAGE(2, 1);
  asm volatile("s_waitcnt vmcnt(6)" ::: "memory");  // tile0 fully landed
  BAR;

  for (int it = 0; it < NKT / 2; ++it) {
    const int notlast = (it < NKT / 2 - 1);
    // ================= tile 2it (buf0) =================
    // Pa: ALL A reads + bq<-NQ0 (20 ds_reads); stage [2it+1].Bh1.
    LDA(af0, 0, 0);
    LDBQ(0, 0);
    LDA(af1, 0, 1);
    STAGE(3, 2 * it + 1);
    BAR; LGKM8; PRIO1; MFMAQ(af0, 0, 0); PRIO0; BAR;
    // Pb: af1 ready; Q10; reload bq<-NQ1 AFTER the MFMA.
    LGKM0; PRIO1; MFMAQ(af1, 1, 0); PRIO0;
    LDBQ(0, 1);
    BAR;
    // Pc: stage [2it+2].Ah0 (A reads completed cross-wave at Pb's BAR)
    if (notlast) STAGE(0, 2 * it + 2);
    BAR; LGKM0; PRIO1; MFMAQ(af0, 0, 1); PRIO0; BAR;
    // Pd: stage [2it+2].{Ah1,Bh0}; reg-only Q11; counted vmcnt gate
    if (notlast) { STAGE(1, 2 * it + 2); STAGE(2, 2 * it + 2); }
    BAR; PRIO1; MFMAQ(af1, 1, 1); PRIO0;
    if (notlast) asm volatile("s_waitcnt vmcnt(6)" ::: "memory");
    else         asm volatile("s_waitcnt vmcnt(0)" ::: "memory");
    BAR;  // tile 2it+1 fully landed in buf1
    // ================= tile 2it+1 (buf1) =================
    LDA(af0, 1, 0);
    LDBQ(1, 0);
    LDA(af1, 1, 1);
    if (notlast) STAGE(3, 2 * it + 2);
    BAR; LGKM8; PRIO1; MFMAQ(af0, 0, 0); PRIO0; BAR;
    LGKM0; PRIO1; MFMAQ(af1, 1, 0); PRIO0;
    LDBQ(1, 1);
    BAR;
    if (notlast) STAGE(0, 2 * it + 3);
    BAR; LGKM0; PRIO1; MFMAQ(af0, 0, 1); PRIO0; BAR;
    if (notlast) { STAGE(1, 2 * it + 3); STAGE(2, 2 * it + 3); }
    BAR; PRIO1; MFMAQ(af1, 1, 1); PRIO0;
    if (notlast) asm volatile("s_waitcnt vmcnt(6)" ::: "memory");
    BAR;  // tile 2it+2 fully landed in buf0
  }

  // ---- epilogue: C/D layout col = lane&15, row = (lane>>4)*4 + reg ----
  int rbase = m0 + wm + fq * 4;
#pragma unroll
  for (int nr = 0; nr < 4; ++nr) {
    int col = n0 + wn + nr * 16 + fr;
    float be = benc[col];
#pragma unroll
    for (int mr = 0; mr < 8; ++mr) {
      int row = rbase + mr * 16;
#pragma unroll
      for (int r = 0; r < 4; ++r)
        Z[(size_t)(row + r) * LL + col] = acc[mr][nr][r] + be;
    }
  }
}

// ---------------------------------------------------------------------------
// Kernel 4 (FUSED topk+fixup): per-row top-64 on |zhat|.
// HISTOGRAM CUT (this round): one binning pass of keys >= 2.0 into a
// 512-bucket LDS histogram over bits 30..16 (bucket = (key>>16) - 0x4000,
// [2,16) span, clamp -> 511), then a single wave-0 reverse suffix-scan finds
// the LARGEST 16-bit-granular prefix c with count(>=c) >= KT — exactly the
// radix descent's cut (when count(>=2.0) >= KT the radix cut is >= 2.0 and
// all its counts restrict to the binned keys; same granularity -> identical
// cut -> identical TAU window -> identical output). Sequential depth: 1 data
// pass + ~20 scan steps + 3 barriers, vs 15 passes + 15 barriers.
// Fallback (sentinel cut): full 15-round radix, verbatim, when total < KT or
// cut lands in the clamp bucket. Fixup: unified exact-fp64 Wt dots (r9 form).
// ---------------------------------------------------------------------------
__global__ __launch_bounds__(512) void topkfix_kernel(
    const float* __restrict__ Z, const float* __restrict__ X32,
    const float* __restrict__ benc, const float* __restrict__ Wt,
    float* __restrict__ ZS, int* __restrict__ TKI, float* __restrict__ TKV,
    int r0) {
  int lrow = blockIdx.x, grow = r0 + lrow, t = threadIdx.x;
  const float* zr = Z + (size_t)lrow * LL;
  float* zs = ZS + (size_t)lrow * LL;

  __shared__ int hist[512];
  __shared__ unsigned cutsh;
  __shared__ int red[2][8];
  __shared__ unsigned nsel, ntie;
  __shared__ int widx[WCAP];

  hist[t & 511] = 0;  // 512 threads cover all buckets (t<512)
  if (t == 0) { cutsh = 0xFFFFFFFFu; nsel = 0; ntie = 0; }
  __syncthreads();

  // ---- load keys + zero zs + histogram keys >= 2.0 ----
  uint4 kv[8];  // |zhat| bit keys, 32 per thread
#pragma unroll
  for (int i = 0; i < 8; ++i) {
    float4 v = ((const float4*)zr)[t + i * 512];
    kv[i].x = __float_as_uint(v.x) & 0x7fffffffu;
    kv[i].y = __float_as_uint(v.y) & 0x7fffffffu;
    kv[i].z = __float_as_uint(v.z) & 0x7fffffffu;
    kv[i].w = __float_as_uint(v.w) & 0x7fffffffu;
  }
  float4 z4 = {0.f, 0.f, 0.f, 0.f};
#pragma unroll
  for (int i = 0; i < 8; ++i) ((float4*)zs)[t + i * 512] = z4;

  const unsigned thrKey = 0x40000000u;  // 2.0f
#pragma unroll
  for (int i = 0; i < 8; ++i) {
    unsigned k4[4] = {kv[i].x, kv[i].y, kv[i].z, kv[i].w};
#pragma unroll
    for (int q = 0; q < 4; ++q) {
      if (k4[q] >= thrKey) {
        int b = (int)((k4[q] >> 16) - 0x4000u);
        if (b > 511) b = 511;
        atomicAdd(&hist[b], 1);
      }
    }
  }
  __syncthreads();

  // ---- wave-0 reverse suffix-scan: largest b with count(>= bucket b) >= KT
  if (t < 64) {
    int partial[8];
    int s = 0;
    int base_r = t * 8;  // r = 511 - b (reverse index)
#pragma unroll
    for (int q = 0; q < 8; ++q) { partial[q] = hist[511 - (base_r + q)]; s += partial[q]; }
    int sc = s;  // inclusive scan over lanes
#pragma unroll
    for (int off = 1; off < 64; off <<= 1) {
      int up = __shfl_up(sc, off, 64);
      if (t >= off) sc += up;
    }
    int pre = sc - s;                       // exclusive prefix
    int total = __shfl(sc, 63, 64);         // count(keys >= 2.0)
    if (total >= KT && pre < KT && pre + s >= KT) {
      int run = pre, rstar = -1;
#pragma unroll
      for (int q = 0; q < 8; ++q) {
        run += partial[q];
        if (run >= KT && rstar < 0) rstar = base_r + q;
      }
      int bstar = 511 - rstar;
      cutsh = (bstar == 511) ? 0xFFFFFFFFu
                             : (((unsigned)(0x4000 + bstar)) << 16);
    }
  }
  __syncthreads();

  unsigned cut = cutsh;
  if (cut == 0xFFFFFFFFu) {
    // fallback: original block-wide 15-round radix (general inputs / clamp)
    cut = 0;
    for (int bit = 30; bit >= 16; --bit) {
      int ph = bit & 1;
      unsigned ct = cut | (1u << bit);
      int cnt = 0;
#pragma unroll
      for (int i = 0; i < 8; ++i)
        cnt += (kv[i].x >= ct) + (kv[i].y >= ct) + (kv[i].z >= ct) + (kv[i].w >= ct);
      for (int off = 32; off > 0; off >>= 1) cnt += __shfl_down(cnt, off, 64);
      if ((t & 63) == 0) red[ph][t >> 6] = cnt;
      __syncthreads();
      int total = 0;
#pragma unroll
      for (int wv = 0; wv < 8; ++wv) total += red[ph][wv];
      if (total >= KT) cut = ct;
    }
  }

  float c16 = __uint_as_float(cut);
  float cnx = __uint_as_float(cut + 0x10000u);
  float chi = cnx + TAU;
  float clo = c16 - TAU; if (clo < 0.f) clo = 0.f;
  unsigned hiKey = __float_as_uint(chi);
  unsigned loKey = (clo > 0.f) ? __float_as_uint(clo) : 0u;

#pragma unroll
  for (int i = 0; i < 8; ++i) {
    int base = 4 * (t + i * 512);
    unsigned k4[4] = {kv[i].x, kv[i].y, kv[i].z, kv[i].w};
#pragma unroll
    for (int q = 0; q < 4; ++q) {
      unsigned key = k4[q];
      int idx = base + q;
      if (key > hiKey) {  // sure: count(> bucket_hi + TAU) <= 63 by invariant
        unsigned p = atomicAdd(&nsel, 1u);
        if (p < KT) {
          float v = zr[idx];
          TKI[grow * KT + p] = idx;
          TKV[grow * KT + p] = v;
          zs[idx] = v;
        }
      } else if (key >= loKey) {
        unsigned p = atomicAdd(&ntie, 1u);
        if (p < WCAP) widx[p] = idx;
      }
    }
  }
  __syncthreads();
  int ns = (int)nsel; if (ns > KT) ns = KT;
  // insurance: pre-fill deferred slots (fixup overwrites; under-coverage
  // degrades to benign zeros, not poison)
  if (t >= ns && t < KT) { TKI[grow * KT + t] = 0; TKV[grow * KT + t] = 0.f; }
  int wcnt = (int)ntie; if (wcnt > WCAP) wcnt = WCAP;
  int deferred = KT - ns;
  if (deferred <= 0) return;              // uniform exit
  if (deferred > wcnt) deferred = wcnt;   // safety (tau violation; soft)

  // ---- phase 2: fixup from LDS-resident window ----
  if (wcnt == deferred) {  // uncontested: take all (zhat values)
    if (t < wcnt) {
      int idx = widx[t];
      float v = zr[idx];
      TKI[grow * KT + ns + t] = idx;
      TKV[grow * KT + ns + t] = v;
      zs[idx] = v;
    }
    return;
  }

  // contested: exact fp64 dot from contiguous fp32 Wt rows, one candidate
  // per wave (error ~1e-13 from accumulation order only)
  int wid = t >> 6, ln = t & 63;
  __shared__ float xs[DD];
  __shared__ double wz[WCAP];
  for (int i = t; i < DD; i += 512) xs[i] = X32[(size_t)grow * DD + i];
  __syncthreads();
  for (int j = wid; j < wcnt; j += 8) {
    int idx = widx[j];
    const float* wrow = Wt + (size_t)idx * DD;
    double p = 0.0;
#pragma unroll
    for (int kb = 0; kb < 8; ++kb) {
      int k = kb * 256 + ln * 4;
      f32x4 w4 = *(const f32x4*)(wrow + k);
      f32x4 x4 = *(const f32x4*)(xs + k);
#pragma unroll
      for (int e = 0; e < 4; ++e)
        p += (double)x4[e] * (double)w4[e];
    }
    for (int off = 32; off > 0; off >>= 1) p += __shfl_down(p, off, 64);
    if (ln == 0) wz[j] = p + (double)benc[idx];
  }
  __syncthreads();

  if (t == 0) {
    int taken = 0;
    for (int s = 0; s < deferred; ++s) {
      int best = -1; double bv = -1.0;
      for (int j = 0; j < wcnt; ++j) {
        if (taken & (1 << j)) continue;
        double a = fabs(wz[j]);
        if (best < 0 || a > bv || (a == bv && widx[j] < widx[best])) { best = j; bv = a; }
      }
      taken |= (1 << best);
      int idx = widx[best];
      float v = (float)wz[best];
      TKI[grow * KT + ns + s] = idx;
      TKV[grow * KT + ns + s] = v;
      zs[idx] = v;
    }
  }
}

// ---------------------------------------------------------------------------
// Kernel 6: decode  recon[b,d] = b_dec[d] + sum_j val_j * Wh[idx_j, d]
// ---------------------------------------------------------------------------
__global__ __launch_bounds__(256) void decode_kernel(
    const u16* __restrict__ Wh, const float* __restrict__ bdec,
    const int* __restrict__ TKI, const float* __restrict__ TKV,
    float* __restrict__ OUT) {
  int row = blockIdx.x, t = threadIdx.x;
  __shared__ int sidx[KT];
  __shared__ float sval[KT];
  if (t < KT) {
    sidx[t] = TKI[row * KT + t] & (LL - 1);
    sval[t] = TKV[row * KT + t];
  }
  __syncthreads();
  int d0 = t * 8;
  float acc[8] = {0.f, 0.f, 0.f, 0.f, 0.f, 0.f, 0.f, 0.f};
#pragma unroll 16
  for (int j = 0; j < KT; ++j) {
    const u16x8 wv = *(const u16x8*)(Wh + (size_t)sidx[j] * DD + d0);
    float v = sval[j];
#pragma unroll
    for (int e = 0; e < 8; ++e) acc[e] = fmaf(v, bf2f(wv[e]), acc[e]);
  }
  float4 o0, o1;
  o0.x = acc[0] + bdec[d0 + 0]; o0.y = acc[1] + bdec[d0 + 1];
  o0.z = acc[2] + bdec[d0 + 2]; o0.w = acc[3] + bdec[d0 + 3];
  o1.x = acc[4] + bdec[d0 + 4]; o1.y = acc[5] + bdec[d0 + 5];
  o1.z = acc[6] + bdec[d0 + 6]; o1.w = acc[7] + bdec[d0 + 7];
  float* dst = OUT + (size_t)row * DD + d0;
  *(float4*)dst = o0;
  *(float4*)(dst + 4) = o1;
}

// ---------------------------------------------------------------------------
// ws layout (ws = 1152 MiB per round-4 fillBuffer WRITE_SIZE):
//  [Xh 16M][Wh 64M][Wt 128M][TKI 1M][TKV 1M][Zc 268M @ single chunk]
// ---------------------------------------------------------------------------
extern "C" void kernel_launch(void* const* d_in, const int* in_sizes, int n_in,
                              void* d_out, int out_size, void* d_ws,
                              size_t ws_size, hipStream_t stream) {
  const float* X = (const float*)d_in[0];     // [4096, 2048] fp32
  const float* W = (const float*)d_in[1];     // [2048, 16384] fp32
  const float* benc = (const float*)d_in[2];  // [16384] fp32
  const float* bdec = (const float*)d_in[3];  // [2048] fp32

  char* ws = (char*)d_ws;
  const size_t XH_B = (size_t)NB * DD * 2;      // 16,777,216
  const size_t WH_B = (size_t)LL * DD * 2;      // 67,108,864
  const size_t WT_B = (size_t)LL * DD * 4;      // 134,217,728
  const size_t TKI_B = (size_t)NB * KT * 4;     // 1,048,576
  u16* Xh = (u16*)ws;
  u16* Wh = (u16*)(ws + XH_B);
  float* Wt = (float*)(ws + XH_B + WH_B);
  int* TKI = (int*)(ws + XH_B + WH_B + WT_B);
  float* TKV = (float*)(ws + XH_B + WH_B + WT_B + TKI_B);
  float* Zc = (float*)(ws + XH_B + WH_B + WT_B + 2 * TKI_B);

  size_t fixed = XH_B + WH_B + WT_B + 2 * TKI_B;
  size_t avail = (ws_size > fixed) ? (ws_size - fixed) : 0;
  int chunk = (int)(avail / ((size_t)LL * 4));
  chunk = (chunk / TBM) * TBM;
  if (chunk > NB) chunk = NB;
  if (chunk < TBM) chunk = TBM;

  float* out_recon = (float*)d_out;                    // [4096, 2048]
  float* out_zs = (float*)d_out + (size_t)NB * DD;     // [4096, 16384]

  prep_x<<<NB * DD / 1024, 256, 0, stream>>>(X, Xh);
  prep_w<<<dim3(LL / 64, DD / 64), 256, 0, stream>>>(W, Wh, Wt);
  for (int r0 = 0; r0 < NB; r0 += chunk) {
    int rows = NB - r0; if (rows > chunk) rows = chunk;
    encode_gemm<<<dim3(LL / TBN, rows / TBM), 512, 0, stream>>>(
        Xh + (size_t)r0 * DD, Wh, benc, Zc);
    topkfix_kernel<<<rows, 512, 0, stream>>>(
        Zc, X, benc, Wt, out_zs + (size_t)r0 * LL, TKI, TKV, r0);
  }
  decode_kernel<<<NB, 256, 0, stream>>>(Wh, bdec, TKI, TKV, out_recon);
}

// Round 11
// 1021.043 us; speedup vs baseline: 1.1725x; 1.0523x over previous
//
#include <hip/hip_runtime.h>
#include <stdint.h>

// Problem constants (B, D, L, K from the reference). fp32 I/O per reference.
#define NB 4096
#define DD 2048
#define LL 16384
#define KT 64
#define WCAP 24        // window candidate cap per row
#define TAU 1.2e-2f    // sure/window margin: 5.7 sigma of zhat error (hh-only)

typedef unsigned short u16;
typedef __bf16 bf16x8 __attribute__((ext_vector_type(8)));
typedef float f32x4 __attribute__((ext_vector_type(4)));
typedef unsigned short u16x4 __attribute__((ext_vector_type(4)));
typedef unsigned short u16x8 __attribute__((ext_vector_type(8)));

__device__ __forceinline__ float bf2f(u16 b) {
  return __uint_as_float(((unsigned)b) << 16);
}
__device__ __forceinline__ u16 f2bf(float f) {
  unsigned u = __float_as_uint(f);
  unsigned r = u + 0x7fffu + ((u >> 16) & 1u);  // RNE
  return (u16)(r >> 16);
}

// ---------------------------------------------------------------------------
// Kernel 1: X fp32 -> Xh bf16 (hi part only; fixup reads fp32 X directly)
// ---------------------------------------------------------------------------
__global__ __launch_bounds__(256) void prep_x(const float* __restrict__ X,
                                              u16* __restrict__ Xh) {
  int i = (blockIdx.x * 256 + threadIdx.x) * 4;
  float4 v = *(const float4*)(X + i);
  u16x4 h;
  h[0] = f2bf(v.x); h[1] = f2bf(v.y); h[2] = f2bf(v.z); h[3] = f2bf(v.w);
  *(u16x4*)(Xh + i) = h;
}

// ---------------------------------------------------------------------------
// Kernel 2: transpose W fp32 [2048,16384] -> Wh bf16 [16384,2048] (GEMM +
// decode) and Wt fp32 [16384,2048] (exact fixup dots).
// ---------------------------------------------------------------------------
__global__ __launch_bounds__(256) void prep_w(const float* __restrict__ W,
                                              u16* __restrict__ Wh,
                                              float* __restrict__ Wt) {
  __shared__ float tile[64][65];  // +1 pad breaks write-phase bank aliasing
  int l0 = blockIdx.x * 64, d0 = blockIdx.y * 64;
  int t = threadIdx.x;
  int lx = (t & 15) * 4;
  int dq = t >> 4;
#pragma unroll
  for (int p = 0; p < 4; ++p) {
    int d = dq + p * 16;
    float4 v = *(const float4*)(W + (size_t)(d0 + d) * LL + l0 + lx);
    tile[d][lx + 0] = v.x; tile[d][lx + 1] = v.y;
    tile[d][lx + 2] = v.z; tile[d][lx + 3] = v.w;
  }
  __syncthreads();
  int dx = (t & 15) * 4;
  int lq = t >> 4;
#pragma unroll
  for (int p = 0; p < 4; ++p) {
    int l = lq + p * 16;
    u16x4 h;
    float4 wv;
#pragma unroll
    for (int q = 0; q < 4; ++q) {
      float w = tile[dx + q][l];
      h[q] = f2bf(w);
      ((float*)&wv)[q] = w;
    }
    size_t o = (size_t)(l0 + l) * DD + d0 + dx;
    *(u16x4*)(Wh + o) = h;
    *(float4*)(Wt + o) = wv;
  }
}

// ---------------------------------------------------------------------------
// Kernel 3: encode GEMM  zhat = Xh·Wh^T + benc
// Round-2 7-barrier read-ahead schedule — the measured 283-288 us variant.
// FROZEN.
// ---------------------------------------------------------------------------
#define TBM 256
#define TBN 256
#define TBK 64
#define NKT (DD / TBK)  // 32 K-tiles, 16 iterations of 2

__device__ __forceinline__ void async16(const u16* g, u16* l) {
  __builtin_amdgcn_global_load_lds(
      (const __attribute__((address_space(1))) unsigned int*)g,
      (__attribute__((address_space(3))) unsigned int*)l, 16, 0, 0);
}

// HF: 0=A.h0 1=A.h1 2=B.h0 3=B.h1 (compile-time); TAU_ = K-tile index.
#define STAGE(HF, TAU_)                                                      \
  do {                                                                       \
    const u16* g_ = ((HF) < 2 ? Abase : Bbase) +                             \
                    (size_t)(((HF)&1) * 128 + rr) * DD + ((TAU_) << 6) +     \
                    scol;                                                    \
    u16* l_ = ((HF) < 2 ? As : Bs) + ((TAU_)&1) * (TBM * TBK) +              \
              (((HF)&1) * 128) * TBK + t * 8;                                \
    async16(g_, l_);                                                         \
    async16(g_ + (size_t)64 * DD, l_ + 4096);                                \
  } while (0)

// Load one A m-quadrant (4 mreps x 2 ksubs = 8 x ds_read_b128) into DST.
#define LDA(DST, DB, MQ)                                                     \
  do {                                                                       \
    const u16* p_ = As + (DB) * (TBM * TBK) + (wm + (MQ)*64 + fr) * TBK;     \
    _Pragma("unroll") for (int i_ = 0; i_ < 4; ++i_) {                       \
      DST[i_][0] = *(const bf16x8*)(p_ + i_ * (16 * TBK) + c0);              \
      DST[i_][1] = *(const bf16x8*)(p_ + i_ * (16 * TBK) + c1);              \
    }                                                                        \
  } while (0)

// Load one B n-quadrant (2 nreps x 2 ksubs = 4 x ds_read_b128) into bq.
#define LDBQ(DB, NQ)                                                         \
  do {                                                                       \
    const u16* p_ = Bs + (DB) * (TBN * TBK) + (wn + (NQ)*32 + fr) * TBK;     \
    _Pragma("unroll") for (int j_ = 0; j_ < 2; ++j_) {                       \
      bq[j_][0] = *(const bf16x8*)(p_ + j_ * (16 * TBK) + c0);               \
      bq[j_][1] = *(const bf16x8*)(p_ + j_ * (16 * TBK) + c1);               \
    }                                                                        \
  } while (0)

// One C-quadrant x K=64: 4x2 frags x 2 chained ksubs = 16 MFMA.
#define MFMAQ(AF, MQ, NQ)                                                    \
  do {                                                                       \
    _Pragma("unroll") for (int i_ = 0; i_ < 4; ++i_)                         \
        _Pragma("unroll") for (int j_ = 0; j_ < 2; ++j_) {                   \
      f32x4 a_ = acc[(MQ)*4 + i_][(NQ)*2 + j_];                              \
      a_ = __builtin_amdgcn_mfma_f32_16x16x32_bf16(AF[i_][0], bq[j_][0], a_, \
                                                   0, 0, 0);                 \
      a_ = __builtin_amdgcn_mfma_f32_16x16x32_bf16(AF[i_][1], bq[j_][1], a_, \
                                                   0, 0, 0);                 \
      acc[(MQ)*4 + i_][(NQ)*2 + j_] = a_;                                    \
    }                                                                        \
  } while (0)

#define BAR __builtin_amdgcn_s_barrier()
#define LGKM0 asm volatile("s_waitcnt lgkmcnt(0)")
#define LGKM8 asm volatile("s_waitcnt lgkmcnt(8)")
#define PRIO1 __builtin_amdgcn_s_setprio(1)
#define PRIO0 __builtin_amdgcn_s_setprio(0)

__global__ __launch_bounds__(512, 2) void encode_gemm(
    const u16* __restrict__ Xh,   // [rows,2048] (pre-offset to chunk)
    const u16* __restrict__ Wh,   // [16384,2048]
    const float* __restrict__ benc,
    float* __restrict__ Z) {      // [rows,16384]
  __shared__ u16 As[2 * TBM * TBK];  // 64 KB (2 dbuf x 256 x 64)
  __shared__ u16 Bs[2 * TBN * TBK];  // 64 KB
  int t = threadIdx.x;
  int m0 = blockIdx.y * TBM;
  int n0 = blockIdx.x * TBN;

  int lane = t & 63, w = t >> 6;
  int wm = (w & 1) * 128;   // wave M offset (2 waves in M)
  int wn = (w >> 1) * 64;   // wave N offset (4 waves in N)
  int fr = lane & 15;
  int fq = lane >> 4;
  // swizzled ds_read column granules (elements), ksub 0 / ksub 1
  int c0 = ((fq ^ (fr & 7)) << 3);
  int c1 = (((4 + fq) ^ (fr & 7)) << 3);
  // staging: thread t covers row rr (per q: +0/+64), slot t&7, swizzled src
  int rr = t >> 3;
  int scol = (((t & 7) ^ (rr & 7)) << 3);

  const u16* Abase = Xh + (size_t)m0 * DD;
  const u16* Bbase = Wh + (size_t)n0 * DD;

  f32x4 acc[8][4] = {};
  bf16x8 af0[4][2], af1[4][2], bq[2][2];

  // ---- prologue: stage tile0 (4 halves) + tile1 {Ah0,Ah1,Bh0} ----
  STAGE(0, 0); STAGE(1, 0); STAGE(2, 0); STAGE(3, 0);
  asm volatile("s_waitcnt vmcnt(4)" ::: "memory");
  STAGE(0, 1); STAGE(1, 1); STAGE(2, 1);
  asm volatile("s_waitcnt vmcnt(6)" ::: "memory");  // tile0 fully landed
  BAR;

  for (int it = 0; it < NKT / 2; ++it) {
    const int notlast = (it < NKT / 2 - 1);
    // ================= tile 2it (buf0) =================
    // Pa: ALL A reads + bq<-NQ0 (20 ds_reads); stage [2it+1].Bh1.
    LDA(af0, 0, 0);
    LDBQ(0, 0);
    LDA(af1, 0, 1);
    STAGE(3, 2 * it + 1);
    BAR; LGKM8; PRIO1; MFMAQ(af0, 0, 0); PRIO0; BAR;
    // Pb: af1 ready; Q10; reload bq<-NQ1 AFTER the MFMA.
    LGKM0; PRIO1; MFMAQ(af1, 1, 0); PRIO0;
    LDBQ(0, 1);
    BAR;
    // Pc: stage [2it+2].Ah0 (A reads completed cross-wave at Pb's BAR)
    if (notlast) STAGE(0, 2 * it + 2);
    BAR; LGKM0; PRIO1; MFMAQ(af0, 0, 1); PRIO0; BAR;
    // Pd: stage [2it+2].{Ah1,Bh0}; reg-only Q11; counted vmcnt gate
    if (notlast) { STAGE(1, 2 * it + 2); STAGE(2, 2 * it + 2); }
    BAR; PRIO1; MFMAQ(af1, 1, 1); PRIO0;
    if (notlast) asm volatile("s_waitcnt vmcnt(6)" ::: "memory");
    else         asm volatile("s_waitcnt vmcnt(0)" ::: "memory");
    BAR;  // tile 2it+1 fully landed in buf1
    // ================= tile 2it+1 (buf1) =================
    LDA(af0, 1, 0);
    LDBQ(1, 0);
    LDA(af1, 1, 1);
    if (notlast) STAGE(3, 2 * it + 2);
    BAR; LGKM8; PRIO1; MFMAQ(af0, 0, 0); PRIO0; BAR;
    LGKM0; PRIO1; MFMAQ(af1, 1, 0); PRIO0;
    LDBQ(1, 1);
    BAR;
    if (notlast) STAGE(0, 2 * it + 3);
    BAR; LGKM0; PRIO1; MFMAQ(af0, 0, 1); PRIO0; BAR;
    if (notlast) { STAGE(1, 2 * it + 3); STAGE(2, 2 * it + 3); }
    BAR; PRIO1; MFMAQ(af1, 1, 1); PRIO0;
    if (notlast) asm volatile("s_waitcnt vmcnt(6)" ::: "memory");
    BAR;  // tile 2it+2 fully landed in buf0
  }

  // ---- epilogue: C/D layout col = lane&15, row = (lane>>4)*4 + reg ----
  int rbase = m0 + wm + fq * 4;
#pragma unroll
  for (int nr = 0; nr < 4; ++nr) {
    int col = n0 + wn + nr * 16 + fr;
    float be = benc[col];
#pragma unroll
    for (int mr = 0; mr < 8; ++mr) {
      int row = rbase + mr * 16;
#pragma unroll
      for (int r = 0; r < 4; ++r)
        Z[(size_t)(row + r) * LL + col] = acc[mr][nr][r] + be;
    }
  }
}

// ---------------------------------------------------------------------------
// Kernel 4 (FUSED topk+fixup+DECODE): per-row top-64 on |zhat| via the
// histogram cut (r10, bit-identical to radix), fixup via exact-fp64 Wt dots,
// and — NEW — the decode for this row fused at the end: the 64 (idx,val)
// pairs stay in LDS (sidx/sval; TKI/TKV global round-trip deleted) and all
// 512 threads compute recon[grow,:] = bdec + sum val_j * Wh[idx_j,:]
// (4 dims/thread, u16x4 loads; per-output fmaf chain order identical to the
// old decode_kernel -> bit-identical recon). Decode's 1 GB L3 gather now
// overlaps other rows' latency bubbles instead of running as a serial
// epilogue kernel. Early-exit paths converge to decode (branches are
// block-uniform: ns/wcnt/deferred from shared counters post-barrier).
// ---------------------------------------------------------------------------
__global__ __launch_bounds__(512) void topkfix_kernel(
    const float* __restrict__ Z, const float* __restrict__ X32,
    const float* __restrict__ benc, const float* __restrict__ Wt,
    const u16* __restrict__ Wh, const float* __restrict__ bdec,
    float* __restrict__ ZS, float* __restrict__ RECON, int r0) {
  int lrow = blockIdx.x, grow = r0 + lrow, t = threadIdx.x;
  const float* zr = Z + (size_t)lrow * LL;
  float* zs = ZS + (size_t)lrow * LL;

  __shared__ int hist[512];
  __shared__ unsigned cutsh;
  __shared__ int red[2][8];
  __shared__ unsigned nsel, ntie;
  __shared__ int widx[WCAP];
  __shared__ int sidx[KT];
  __shared__ float sval[KT];

  hist[t & 511] = 0;  // 512 threads cover all buckets
  if (t == 0) { cutsh = 0xFFFFFFFFu; nsel = 0; ntie = 0; }
  __syncthreads();

  // ---- load keys + zero zs + histogram keys >= 2.0 ----
  uint4 kv[8];  // |zhat| bit keys, 32 per thread
#pragma unroll
  for (int i = 0; i < 8; ++i) {
    float4 v = ((const float4*)zr)[t + i * 512];
    kv[i].x = __float_as_uint(v.x) & 0x7fffffffu;
    kv[i].y = __float_as_uint(v.y) & 0x7fffffffu;
    kv[i].z = __float_as_uint(v.z) & 0x7fffffffu;
    kv[i].w = __float_as_uint(v.w) & 0x7fffffffu;
  }
  float4 z4 = {0.f, 0.f, 0.f, 0.f};
#pragma unroll
  for (int i = 0; i < 8; ++i) ((float4*)zs)[t + i * 512] = z4;

  const unsigned thrKey = 0x40000000u;  // 2.0f
#pragma unroll
  for (int i = 0; i < 8; ++i) {
    unsigned k4[4] = {kv[i].x, kv[i].y, kv[i].z, kv[i].w};
#pragma unroll
    for (int q = 0; q < 4; ++q) {
      if (k4[q] >= thrKey) {
        int b = (int)((k4[q] >> 16) - 0x4000u);
        if (b > 511) b = 511;
        atomicAdd(&hist[b], 1);
      }
    }
  }
  __syncthreads();

  // ---- wave-0 reverse suffix-scan: largest b with count(>= bucket b) >= KT
  if (t < 64) {
    int partial[8];
    int s = 0;
    int base_r = t * 8;  // r = 511 - b (reverse index)
#pragma unroll
    for (int q = 0; q < 8; ++q) { partial[q] = hist[511 - (base_r + q)]; s += partial[q]; }
    int sc = s;  // inclusive scan over lanes
#pragma unroll
    for (int off = 1; off < 64; off <<= 1) {
      int up = __shfl_up(sc, off, 64);
      if (t >= off) sc += up;
    }
    int pre = sc - s;                       // exclusive prefix
    int total = __shfl(sc, 63, 64);         // count(keys >= 2.0)
    if (total >= KT && pre < KT && pre + s >= KT) {
      int run = pre, rstar = -1;
#pragma unroll
      for (int q = 0; q < 8; ++q) {
        run += partial[q];
        if (run >= KT && rstar < 0) rstar = base_r + q;
      }
      int bstar = 511 - rstar;
      cutsh = (bstar == 511) ? 0xFFFFFFFFu
                             : (((unsigned)(0x4000 + bstar)) << 16);
    }
  }
  __syncthreads();

  unsigned cut = cutsh;
  if (cut == 0xFFFFFFFFu) {
    // fallback: original block-wide 15-round radix (general inputs / clamp)
    cut = 0;
    for (int bit = 30; bit >= 16; --bit) {
      int ph = bit & 1;
      unsigned ct = cut | (1u << bit);
      int cnt = 0;
#pragma unroll
      for (int i = 0; i < 8; ++i)
        cnt += (kv[i].x >= ct) + (kv[i].y >= ct) + (kv[i].z >= ct) + (kv[i].w >= ct);
      for (int off = 32; off > 0; off >>= 1) cnt += __shfl_down(cnt, off, 64);
      if ((t & 63) == 0) red[ph][t >> 6] = cnt;
      __syncthreads();
      int total = 0;
#pragma unroll
      for (int wv = 0; wv < 8; ++wv) total += red[ph][wv];
      if (total >= KT) cut = ct;
    }
  }

  float c16 = __uint_as_float(cut);
  float cnx = __uint_as_float(cut + 0x10000u);
  float chi = cnx + TAU;
  float clo = c16 - TAU; if (clo < 0.f) clo = 0.f;
  unsigned hiKey = __float_as_uint(chi);
  unsigned loKey = (clo > 0.f) ? __float_as_uint(clo) : 0u;

#pragma unroll
  for (int i = 0; i < 8; ++i) {
    int base = 4 * (t + i * 512);
    unsigned k4[4] = {kv[i].x, kv[i].y, kv[i].z, kv[i].w};
#pragma unroll
    for (int q = 0; q < 4; ++q) {
      unsigned key = k4[q];
      int idx = base + q;
      if (key > hiKey) {  // sure: count(> bucket_hi + TAU) <= 63 by invariant
        unsigned p = atomicAdd(&nsel, 1u);
        if (p < KT) {
          float v = zr[idx];
          sidx[p] = idx;
          sval[p] = v;
          zs[idx] = v;
        }
      } else if (key >= loKey) {
        unsigned p = atomicAdd(&ntie, 1u);
        if (p < WCAP) widx[p] = idx;
      }
    }
  }
  __syncthreads();
  int ns = (int)nsel; if (ns > KT) ns = KT;
  // insurance: pre-fill deferred slots (fixup overwrites; under-coverage
  // degrades to benign zeros, not poison)
  if (t >= ns && t < KT) { sidx[t] = 0; sval[t] = 0.f; }
  int wcnt = (int)ntie; if (wcnt > WCAP) wcnt = WCAP;
  int deferred = KT - ns;
  if (deferred > wcnt) deferred = wcnt;   // safety (tau violation; soft)

  // ---- phase 2: fixup from LDS-resident window (block-uniform branches) ----
  if (deferred > 0) {
    if (wcnt == deferred) {  // uncontested: take all (zhat values)
      if (t < wcnt) {
        int idx = widx[t];
        float v = zr[idx];
        sidx[ns + t] = idx;
        sval[ns + t] = v;
        zs[idx] = v;
      }
    } else {
      // contested: exact fp64 dot from contiguous fp32 Wt rows, one
      // candidate per wave (error ~1e-13 from accumulation order only)
      int wid = t >> 6, ln = t & 63;
      __shared__ float xs[DD];
      __shared__ double wz[WCAP];
      for (int i = t; i < DD; i += 512) xs[i] = X32[(size_t)grow * DD + i];
      __syncthreads();
      for (int j = wid; j < wcnt; j += 8) {
        int idx = widx[j];
        const float* wrow = Wt + (size_t)idx * DD;
        double p = 0.0;
#pragma unroll
        for (int kb = 0; kb < 8; ++kb) {
          int k = kb * 256 + ln * 4;
          f32x4 w4 = *(const f32x4*)(wrow + k);
          f32x4 x4 = *(const f32x4*)(xs + k);
#pragma unroll
          for (int e = 0; e < 4; ++e)
            p += (double)x4[e] * (double)w4[e];
        }
        for (int off = 32; off > 0; off >>= 1) p += __shfl_down(p, off, 64);
        if (ln == 0) wz[j] = p + (double)benc[idx];
      }
      __syncthreads();

      if (t == 0) {
        int taken = 0;
        for (int s = 0; s < deferred; ++s) {
          int best = -1; double bv = -1.0;
          for (int j = 0; j < wcnt; ++j) {
            if (taken & (1 << j)) continue;
            double a = fabs(wz[j]);
            if (best < 0 || a > bv || (a == bv && widx[j] < widx[best])) { best = j; bv = a; }
          }
          taken |= (1 << best);
          int idx = widx[best];
          float v = (float)wz[best];
          sidx[ns + s] = idx;
          sval[ns + s] = v;
          zs[idx] = v;
        }
      }
    }
  }
  __syncthreads();

  // ---- phase 3: fused decode — recon[grow,:] from LDS sidx/sval ----
  // 512 threads x 4 dims; per-output fmaf chain over j ascending, identical
  // to the old decode_kernel's accumulation order -> bit-identical recon.
  int d0 = t * 4;
  float acc4[4] = {0.f, 0.f, 0.f, 0.f};
#pragma unroll 8
  for (int j = 0; j < KT; ++j) {
    const u16x4 wv = *(const u16x4*)(Wh + (size_t)sidx[j] * DD + d0);
    float v = sval[j];
#pragma unroll
    for (int e = 0; e < 4; ++e) acc4[e] = fmaf(v, bf2f(wv[e]), acc4[e]);
  }
  float4 o;
  o.x = acc4[0] + bdec[d0 + 0];
  o.y = acc4[1] + bdec[d0 + 1];
  o.z = acc4[2] + bdec[d0 + 2];
  o.w = acc4[3] + bdec[d0 + 3];
  *(float4*)(RECON + (size_t)grow * DD + d0) = o;
}

// ---------------------------------------------------------------------------
// ws layout (ws = 1152 MiB per round-4 fillBuffer WRITE_SIZE):
//  [Xh 16M][Wh 64M][Wt 128M][Zc 268M @ single chunk]   (TKI/TKV deleted)
// ---------------------------------------------------------------------------
extern "C" void kernel_launch(void* const* d_in, const int* in_sizes, int n_in,
                              void* d_out, int out_size, void* d_ws,
                              size_t ws_size, hipStream_t stream) {
  const float* X = (const float*)d_in[0];     // [4096, 2048] fp32
  const float* W = (const float*)d_in[1];     // [2048, 16384] fp32
  const float* benc = (const float*)d_in[2];  // [16384] fp32
  const float* bdec = (const float*)d_in[3];  // [2048] fp32

  char* ws = (char*)d_ws;
  const size_t XH_B = (size_t)NB * DD * 2;      // 16,777,216
  const size_t WH_B = (size_t)LL * DD * 2;      // 67,108,864
  const size_t WT_B = (size_t)LL * DD * 4;      // 134,217,728
  u16* Xh = (u16*)ws;
  u16* Wh = (u16*)(ws + XH_B);
  float* Wt = (float*)(ws + XH_B + WH_B);
  float* Zc = (float*)(ws + XH_B + WH_B + WT_B);

  size_t fixed = XH_B + WH_B + WT_B;
  size_t avail = (ws_size > fixed) ? (ws_size - fixed) : 0;
  int chunk = (int)(avail / ((size_t)LL * 4));
  chunk = (chunk / TBM) * TBM;
  if (chunk > NB) chunk = NB;
  if (chunk < TBM) chunk = TBM;

  float* out_recon = (float*)d_out;                    // [4096, 2048]
  float* out_zs = (float*)d_out + (size_t)NB * DD;     // [4096, 16384]

  prep_x<<<NB * DD / 1024, 256, 0, stream>>>(X, Xh);
  prep_w<<<dim3(LL / 64, DD / 64), 256, 0, stream>>>(W, Wh, Wt);
  for (int r0 = 0; r0 < NB; r0 += chunk) {
    int rows = NB - r0; if (rows > chunk) rows = chunk;
    encode_gemm<<<dim3(LL / TBN, rows / TBM), 512, 0, stream>>>(
        Xh + (size_t)r0 * DD, Wh, benc, Zc);
    topkfix_kernel<<<rows, 512, 0, stream>>>(
        Zc, X, benc, Wt, Wh, bdec, out_zs + (size_t)r0 * LL, out_recon, r0);
  }
}